// Round 1
// 1252.632 us; speedup vs baseline: 1.7462x; 1.7462x over previous
//
#include <hip/hip_runtime.h>
#include <math.h>

typedef unsigned short u16;
typedef unsigned int   u32;
typedef __bf16 bf16x8 __attribute__((ext_vector_type(8)));
typedef float  f32x4  __attribute__((ext_vector_type(4)));

#define S_LEN 4096
#define HID   2048
#define NHEAD 16
#define HD    128
#define NW    1024
#define TOK   8192
#define LN10000 9.2103403719761836f
#define NEG_BIG (-1e30f)

__device__ __forceinline__ float b2f(u16 u){
  union { u32 i; float f; } v; v.i = ((u32)u) << 16; return v.f;
}
__device__ __forceinline__ u16 f2b(float f){
  union { float f; u32 i; } v; v.f = f;
  return (u16)((v.i + 0x7FFFu + ((v.i >> 16) & 1u)) >> 16);
}

// ---------------- MFMA GEMM: C(M,N) = A(M,K) @ B(K,N) -----------------------------------
// A: f32 (inputs) or bf16/u16 (ws). B: f32 (weights). C: bf16/u16 or f32 (templated).
// 128x128 tile, BK=32, 4 waves 2x2 (64x64 each), mfma_f32_16x16x32_bf16, convert at stage.
// A-frag: lane holds A[m=lane&15][k=quad*8+j]; B staged transposed ([n][k]) so the same
// contiguous-16B read gives B[n=lane&15][k=quad*8+j]. C/D: col=lane&15, row=quad*4+reg
// (m89/m91-verified). LDS ld 32->40 (80B=5*16B: b128-aligned, 2-way banks only = free).
template<typename TA, typename TC>
__global__ __launch_bounds__(256) void gemm_any(const TA* __restrict__ A,
    const float* __restrict__ Bw, TC* __restrict__ C, int M, int N, int K)
{
  __shared__ u16 As[128*40];
  __shared__ u16 Bs[128*40];
  const int tid  = threadIdx.x;
  const int bM   = blockIdx.y * 128;
  const int bN   = blockIdx.x * 128;
  const int lane = tid & 63;
  const int wid  = tid >> 6;
  const int wm   = wid >> 1, wn = wid & 1;
  const int lrow = lane & 15, quad = lane >> 4;

  f32x4 acc[4][4];
  #pragma unroll
  for (int i = 0; i < 4; i++)
    #pragma unroll
    for (int j = 0; j < 4; j++)
      #pragma unroll
      for (int r = 0; r < 4; r++) acc[i][j][r] = 0.f;

  for (int k0 = 0; k0 < K; k0 += 32){
    // stage A: 128 rows x 32 k, 4 elems/thread/iter
    #pragma unroll
    for (int i = 0; i < 4; i++){
      int c = tid + i*256;
      int row = c >> 3, kc = (c & 7) * 4;
      u16 tmp[4];
      if constexpr (sizeof(TA) == 4){
        float4 v = *(const float4*)&A[(size_t)(bM + row)*K + k0 + kc];
        tmp[0] = f2b(v.x); tmp[1] = f2b(v.y); tmp[2] = f2b(v.z); tmp[3] = f2b(v.w);
      } else {
        *(uint2*)tmp = *(const uint2*)&A[(size_t)(bM + row)*K + k0 + kc];
      }
      *(uint2*)&As[row*40 + kc] = *(uint2*)tmp;
    }
    // stage B transposed: 32 k-rows x 128 n (f32, coalesced float4), scatter to Bs[n][k]
    #pragma unroll
    for (int i = 0; i < 4; i++){
      int c = tid + i*256;
      int kr = c >> 5, nc = (c & 31) * 4;
      float4 v = *(const float4*)&Bw[(size_t)(k0 + kr)*N + bN + nc];
      Bs[(nc+0)*40 + kr] = f2b(v.x);
      Bs[(nc+1)*40 + kr] = f2b(v.y);
      Bs[(nc+2)*40 + kr] = f2b(v.z);
      Bs[(nc+3)*40 + kr] = f2b(v.w);
    }
    __syncthreads();
    bf16x8 af[4], bfv[4];
    #pragma unroll
    for (int mf = 0; mf < 4; mf++)
      af[mf] = *(const bf16x8*)&As[(wm*64 + mf*16 + lrow)*40 + quad*8];
    #pragma unroll
    for (int nf = 0; nf < 4; nf++)
      bfv[nf] = *(const bf16x8*)&Bs[(wn*64 + nf*16 + lrow)*40 + quad*8];
    #pragma unroll
    for (int mf = 0; mf < 4; mf++)
      #pragma unroll
      for (int nf = 0; nf < 4; nf++)
        acc[mf][nf] = __builtin_amdgcn_mfma_f32_16x16x32_bf16(af[mf], bfv[nf], acc[mf][nf], 0, 0, 0);
    __syncthreads();
  }
  #pragma unroll
  for (int mf = 0; mf < 4; mf++){
    #pragma unroll
    for (int nf = 0; nf < 4; nf++){
      int gcol = bN + wn*64 + nf*16 + lrow;
      #pragma unroll
      for (int r = 0; r < 4; r++){
        int grow = bM + wm*64 + mf*16 + quad*4 + r;
        size_t idx = (size_t)grow*N + gcol;
        if constexpr (sizeof(TC) == 4) C[idx] = acc[mf][nf][r];
        else                           C[idx] = f2b(acc[mf][nf][r]);
      }
    }
  }
}

// ---------------- partial interleaved RoPE on q (bf16 ws), in place ---------------------
__global__ void rope_q_kernel(u16* __restrict__ q){
  int gid = blockIdx.x * 256 + threadIdx.x;   // 8192*16*32 pairs
  int t = gid >> 9;
  int r = gid & 511;
  int h = r >> 5;
  int i = r & 31;
  int pos = t & (S_LEN - 1);
  float freq = expf(-(float)i * (LN10000 / 32.f));
  float ang = (float)pos * freq;
  float sn, cs;
  sincosf(ang, &sn, &cs);
  size_t off = (size_t)t*HID + h*HD + 64 + 2*i;
  float a  = b2f(q[off]);
  float bb = b2f(q[off+1]);
  q[off]   = f2b(a*cs - bb*sn);
  q[off+1] = f2b(a*sn + bb*cs);
}

// ---------------- overlapped pooling + k RoPE -------------------------------------------
__global__ void pool_rope_k(const u16* __restrict__ kv, const u16* __restrict__ gate,
                            const float* __restrict__ ape, u16* __restrict__ krot,
                            u16* __restrict__ vout){
  const int d = threadIdx.x;   // 0..127
  const int w = blockIdx.x;    // 0..1023
  const int b = blockIdx.y;
  __shared__ float sh[HD];
  const bool hasprev = (w > 0);
  float gc[4], vc[4], gp[4], vp[4];
  float m = NEG_BIG;
  #pragma unroll
  for (int r = 0; r < 4; r++){
    size_t t = (size_t)(b*S_LEN + w*4 + r)*256;
    vc[r] = b2f(kv[t + 128 + d]);
    gc[r] = b2f(gate[t + 128 + d]) + ape[r*256 + 128 + d];
    m = fmaxf(m, gc[r]);
  }
  if (hasprev){
    #pragma unroll
    for (int r = 0; r < 4; r++){
      size_t t = (size_t)(b*S_LEN + (w-1)*4 + r)*256;
      vp[r] = b2f(kv[t + d]);
      gp[r] = b2f(gate[t + d]) + ape[r*256 + d];
      m = fmaxf(m, gp[r]);
    }
  }
  float s = 0.f, acc = 0.f;
  #pragma unroll
  for (int r = 0; r < 4; r++){
    float e = __expf(gc[r] - m); s += e; acc += e*vc[r];
  }
  if (hasprev){
    #pragma unroll
    for (int r = 0; r < 4; r++){
      float e = __expf(gp[r] - m); s += e; acc += e*vp[r];
    }
  }
  float pooled = acc / s;
  sh[d] = pooled;
  __syncthreads();
  float kr = pooled;
  if (d >= 64){
    int i = (d - 64) >> 1;
    float freq = expf(-(float)i * (LN10000 / 32.f));
    float ang = (float)(4*w) * freq;
    float sn, cs;
    sincosf(ang, &sn, &cs);
    if ((d & 1) == 0) kr = sh[d]*cs - sh[d+1]*sn;
    else              kr = sh[d-1]*sn + sh[d]*cs;
  }
  size_t o = (size_t)(b*NW + w)*HD + d;
  krot[o] = f2b(kr);
  vout[o] = f2b(pooled);
}

// ---------------- MFMA flash attention --------------------------------------------------
// 32 q-rows/block, 64-key chunks, 4 waves (256 thr). QK^T and PV on the MFMA pipe
// (mfma_f32_16x16x32_bf16); online softmax on VALU with f32 scores in LDS, P re-staged
// as bf16. V staged transposed (Vt[d][k]) so the natural B-frag read works; Vt writes are
// 2B-consecutive across 64 lanes (2/bank = free), Vt/Ks/Qs/Ps b128 frag reads are 2-way
// (free, m136). Fully-masked rows (qg<3) produce garbage P but sc==0 in the epilogue
// zeroes the output (same self-healing as the VALU version).
#define QT 32
#define KT 64
#define QSTR 136   // u16 stride (272B, 16B-aligned)
#define KSTR 136   // u16
#define VTSTR 72   // u16 (144B, 16B-aligned)
#define SSTR 68    // f32 stride (272B)
#define PSTR 72    // u16
#define ATT_SCALE 0.088388347648318447f

__global__ __launch_bounds__(256) void attn_kernel(
    const u16* __restrict__ qbuf, const u16* __restrict__ krot,
    const u16* __restrict__ vbuf, const float* __restrict__ sinks,
    u16* __restrict__ attnbuf)
{
  __shared__ u16 Qs[QT*QSTR];
  __shared__ u16 Ks[KT*KSTR];
  __shared__ u16 Vt[HD*VTSTR];
  __shared__ float Ssc[QT*SSTR];
  __shared__ u16 Ps[QT*PSTR];
  __shared__ float red[256];
  __shared__ float mrow[QT], lrow[QT], arow[QT];

  const int tid  = threadIdx.x;
  const int q0   = blockIdx.x * QT;
  const int h    = blockIdx.y;
  const int b    = blockIdx.z;
  const int lane = tid & 63;
  const int wid  = tid >> 6;
  const int wq   = wid >> 1;     // q half-tile (16 rows) this wave owns
  const int wx   = wid & 1;      // k-half for QK^T / d-half for PV
  const int lrw  = lane & 15;
  const int quad = lane >> 4;

  // stage Q once: 32 x 128 bf16, coalesced uint4
  #pragma unroll
  for (int i = 0; i < 2; i++){
    int c = tid + i*256;
    int qi = c >> 4, cc = c & 15;
    *(uint4*)&Qs[qi*QSTR + cc*8] =
      *(const uint4*)&qbuf[(size_t)(b*S_LEN + q0 + qi)*HID + h*HD + cc*8];
  }
  if (tid < QT){ mrow[tid] = NEG_BIG; lrow[tid] = 0.f; }

  f32x4 accO[4];
  #pragma unroll
  for (int nf = 0; nf < 4; nf++)
    #pragma unroll
    for (int r = 0; r < 4; r++) accO[nf][r] = 0.f;

  const int kmax_tile = (q0 + QT - 1 - 3) >> 2;
  int nchunk = (kmax_tile >> 6) + 1;
  if (nchunk > NW/KT) nchunk = NW/KT;

  __syncthreads();

  for (int ch = 0; ch < nchunk; ch++){
    const int kc0 = ch * KT;
    // stage K natural [k][d]: coalesced uint4
    #pragma unroll
    for (int i = 0; i < 4; i++){
      int c = tid + i*256;
      int kl = c >> 4, cc = c & 15;
      *(uint4*)&Ks[kl*KSTR + cc*8] =
        *(const uint4*)&krot[(size_t)(b*NW + kc0 + kl)*HD + cc*8];
    }
    // stage V transposed Vt[d][k]: per-thread kl = tid&63 (L2-resident rows), writes are
    // 64 consecutive u16 across the wave -> 2 lanes/bank (free)
    {
      int kl = tid & 63;
      int dbase = (tid >> 6) * 8;
      #pragma unroll
      for (int i = 0; i < 4; i++){
        int d0 = dbase + i*32;
        u16 tmp[8];
        *(uint4*)tmp = *(const uint4*)&vbuf[(size_t)(b*NW + kc0 + kl)*HD + d0];
        #pragma unroll
        for (int j = 0; j < 8; j++) Vt[(d0+j)*VTSTR + kl] = tmp[j];
      }
    }
    __syncthreads();

    // QK^T: 32x64 scores, wave = (wq: 16 q-rows, wx: 32 k-cols) -> 2 frags x 4 d-iters
    f32x4 accS[2];
    #pragma unroll
    for (int nf = 0; nf < 2; nf++)
      #pragma unroll
      for (int r = 0; r < 4; r++) accS[nf][r] = 0.f;
    #pragma unroll
    for (int d0 = 0; d0 < HD; d0 += 32){
      bf16x8 af = *(const bf16x8*)&Qs[(wq*16 + lrw)*QSTR + d0 + quad*8];
      #pragma unroll
      for (int nf = 0; nf < 2; nf++){
        bf16x8 bf = *(const bf16x8*)&Ks[(wx*32 + nf*16 + lrw)*KSTR + d0 + quad*8];
        accS[nf] = __builtin_amdgcn_mfma_f32_16x16x32_bf16(af, bf, accS[nf], 0, 0, 0);
      }
    }
    #pragma unroll
    for (int nf = 0; nf < 2; nf++)
      #pragma unroll
      for (int r = 0; r < 4; r++)
        Ssc[(wq*16 + quad*4 + r)*SSTR + wx*32 + nf*16 + lrw] = accS[nf][r];
    __syncthreads();

    // softmax pass 1: 8 threads/row, scale+mask, local max
    const int sqi = tid >> 3;
    const int seg = (tid & 7) * 8;
    const int qg  = q0 + sqi;
    float sv[8];
    float lmax = NEG_BIG;
    #pragma unroll
    for (int j = 0; j < 8; j++){
      int kg = kc0 + seg + j;
      float s = Ssc[sqi*SSTR + seg + j];
      s = (qg >= 4*kg + 3) ? s*ATT_SCALE : NEG_BIG;
      sv[j] = s;
      lmax = fmaxf(lmax, s);
    }
    red[tid] = lmax;
    __syncthreads();
    if (tid < QT){
      float mold = mrow[tid];
      float mx = mold;
      #pragma unroll
      for (int j = 0; j < 8; j++) mx = fmaxf(mx, red[tid*8 + j]);
      arow[tid] = __expf(mold - mx);
      mrow[tid] = mx;
    }
    __syncthreads();
    // softmax pass 2: exp, write P bf16, partial row sums (f32 sums kept for final norm)
    {
      float mloc = mrow[sqi];
      float ps = 0.f;
      u16 pb[8];
      #pragma unroll
      for (int j = 0; j < 8; j++){
        float p = __expf(sv[j] - mloc);
        ps += p;
        pb[j] = f2b(p);
      }
      *(uint4*)&Ps[sqi*PSTR + seg] = *(uint4*)pb;
      red[tid] = ps;
    }
    __syncthreads();
    if (tid < QT){
      float sum = 0.f;
      #pragma unroll
      for (int j = 0; j < 8; j++) sum += red[tid*8 + j];
      lrow[tid] = lrow[tid]*arow[tid] + sum;
    }
    // PV: O(32x128) += P(32x64) @ V(64x128); wave = (wq: 16 q-rows, wx: 64 d-cols)
    {
      float al[4];
      #pragma unroll
      for (int r = 0; r < 4; r++) al[r] = arow[wq*16 + quad*4 + r];
      #pragma unroll
      for (int nf = 0; nf < 4; nf++)
        #pragma unroll
        for (int r = 0; r < 4; r++) accO[nf][r] *= al[r];
      #pragma unroll
      for (int kk = 0; kk < KT; kk += 32){
        bf16x8 paf = *(const bf16x8*)&Ps[(wq*16 + lrw)*PSTR + kk + quad*8];
        #pragma unroll
        for (int nf = 0; nf < 4; nf++){
          bf16x8 vbf = *(const bf16x8*)&Vt[(wx*64 + nf*16 + lrw)*VTSTR + kk + quad*8];
          accO[nf] = __builtin_amdgcn_mfma_f32_16x16x32_bf16(paf, vbf, accO[nf], 0, 0, 0);
        }
      }
    }
    __syncthreads();
  }

  // epilogue: sink normalization, write bf16
  const float snk = sinks[h];
  #pragma unroll
  for (int r = 0; r < 4; r++){
    int q = wq*16 + quad*4 + r;
    float m = mrow[q], l = lrow[q];
    float mf = fmaxf(m, snk);
    float em = __expf(m - mf);
    float sc = em / (l*em + __expf(snk - mf));
    size_t o = (size_t)(b*S_LEN + q0 + q)*HID + h*HD + wx*64 + lrw;
    #pragma unroll
    for (int nf = 0; nf < 4; nf++)
      attnbuf[o + nf*16] = f2b(accO[nf][r] * sc);
  }
}

// ---------------------------------------------------------------------------------------
extern "C" void kernel_launch(void* const* d_in, const int* in_sizes, int n_in,
                              void* d_out, int out_size, void* d_ws, size_t ws_size,
                              hipStream_t stream)
{
  const float* hidden = (const float*)d_in[0];
  const float* wq     = (const float*)d_in[1];
  const float* wkv    = (const float*)d_in[2];
  const float* wgate  = (const float*)d_in[3];
  const float* ape    = (const float*)d_in[4];
  const float* sinks  = (const float*)d_in[5];
  const float* wo     = (const float*)d_in[6];

  u16* qbuf    = (u16*)d_ws;                        // 8192*2048 bf16
  u16* kvbuf   = qbuf    + (size_t)TOK*HID;         // 8192*256
  u16* gatebuf = kvbuf   + (size_t)TOK*256;         // 8192*256
  u16* krot    = gatebuf + (size_t)TOK*256;         // 2*1024*128
  u16* vbuf    = krot    + (size_t)2*NW*HD;         // 2*1024*128
  u16* attnbuf = vbuf    + (size_t)2*NW*HD;         // 8192*2048

  gemm_any<float,u16><<<dim3(HID/128, TOK/128), 256, 0, stream>>>(hidden, wq,    qbuf,    TOK, HID, HID);
  gemm_any<float,u16><<<dim3(256/128, TOK/128), 256, 0, stream>>>(hidden, wkv,   kvbuf,   TOK, 256, HID);
  gemm_any<float,u16><<<dim3(256/128, TOK/128), 256, 0, stream>>>(hidden, wgate, gatebuf, TOK, 256, HID);
  rope_q_kernel<<<(TOK*NHEAD*32)/256, 256, 0, stream>>>(qbuf);
  pool_rope_k<<<dim3(NW, 2), 128, 0, stream>>>(kvbuf, gatebuf, ape, krot, vbuf);
  attn_kernel<<<dim3(S_LEN/QT, NHEAD, 2), 256, 0, stream>>>(qbuf, krot, vbuf, sinks, attnbuf);
  // OUTPUT IS F32 (reference returns float32).
  gemm_any<u16,float><<<dim3(HID/128, TOK/128), 256, 0, stream>>>(attnbuf, wo, (float*)d_out, TOK, HID, HID);
}

// Round 2
// 631.834 us; speedup vs baseline: 3.4620x; 1.9825x over previous
//
#include <hip/hip_runtime.h>
#include <math.h>

typedef unsigned short u16;
typedef unsigned int   u32;
typedef __bf16 bf16x8 __attribute__((ext_vector_type(8)));
typedef float  f32x4  __attribute__((ext_vector_type(4)));

#define S_LEN 4096
#define HID   2048
#define NHEAD 16
#define HD    128
#define NW    1024
#define TOK   8192
#define LN10000 9.2103403719761836f
#define NEG_BIG (-1e30f)

__device__ __forceinline__ float b2f(u16 u){
  union { u32 i; float f; } v; v.i = ((u32)u) << 16; return v.f;
}
__device__ __forceinline__ u16 f2b(float f){
  union { float f; u32 i; } v; v.f = f;
  return (u16)((v.i + 0x7FFFu + ((v.i >> 16) & 1u)) >> 16);
}

// ---------------- one-time f32 -> bf16 convert (hidden), 8 elems/thread -----------------
__global__ __launch_bounds__(256) void cvt_bf16(const float* __restrict__ in,
                                                u16* __restrict__ out){
  size_t i = (size_t)blockIdx.x*256 + threadIdx.x;
  float4 a = ((const float4*)in)[2*i];
  float4 b = ((const float4*)in)[2*i+1];
  u16 t[8];
  t[0]=f2b(a.x); t[1]=f2b(a.y); t[2]=f2b(a.z); t[3]=f2b(a.w);
  t[4]=f2b(b.x); t[5]=f2b(b.y); t[6]=f2b(b.z); t[7]=f2b(b.w);
  *(uint4*)&out[i*8] = *(uint4*)t;
}

// ---------------- one-time weight transpose+convert: f32[K][N] -> bf16[N][K] ------------
// 32x32 LDS tile, [32][33] pad = conflict-free; writes 64B runs (coalesced enough for
// a ~56MB total one-time cost).
__global__ __launch_bounds__(256) void transpose_w(const float* __restrict__ in,
    u16* __restrict__ out, int K, int N){
  __shared__ float t[32][33];
  const int n0 = blockIdx.x*32, k0 = blockIdx.y*32;
  const int c = threadIdx.x & 31, r8 = threadIdx.x >> 5;
  #pragma unroll
  for (int i = 0; i < 4; i++)
    t[r8 + i*8][c] = in[(size_t)(k0 + r8 + i*8)*N + n0 + c];
  __syncthreads();
  #pragma unroll
  for (int i = 0; i < 4; i++)
    out[(size_t)(n0 + r8 + i*8)*K + k0 + c] = f2b(t[c][r8 + i*8]);
}

// ---------------- m97-structure bf16 GEMM: C(M,N) = A(M,K) @ Bt(N,K)^T ------------------
// 128x128 tile, BK=32, 4 waves 2x2, global_load_lds width-16 DMA staging (no VALU, no
// reg round-trip), linear LDS [row][32] (frag read = contiguous-1KB bijection, conflict-
// free). A and Bt both bf16 row-major-K, so staging is identical for both. C/D layout
// col=lane&15, row=quad*4+reg (m89/m91-verified, same as harness-verified gemm_any).
typedef __attribute__((address_space(3))) u16 as3_u16;
typedef __attribute__((address_space(1))) const u16 as1_u16;
__device__ __forceinline__ void gload16(const u16* g, u16* l){
  __builtin_amdgcn_global_load_lds((as1_u16*)g, (as3_u16*)l, 16, 0, 0);
}

template<typename TC>
__global__ __launch_bounds__(256) void gemm_bf16(const u16* __restrict__ A,
    const u16* __restrict__ Bt, TC* __restrict__ C, int M, int N, int K)
{
  __shared__ u16 As[128*32];
  __shared__ u16 Bs[128*32];
  const int tid  = threadIdx.x;
  const int bM   = blockIdx.y * 128;
  const int bN   = blockIdx.x * 128;
  const int lane = tid & 63;
  const int w    = tid >> 6;
  const int wm   = w >> 1, wn = w & 1;
  const int lrow = lane & 15, quad = lane >> 4;
  const int srow = lane >> 2, skc = (lane & 3) * 8;

  // per-lane global staging bases: wave w covers rows [w*32, w*32+32)
  const u16* Ab = &A [(size_t)(bM + w*32 + srow)*K + skc];
  const u16* Bb = &Bt[(size_t)(bN + w*32 + srow)*K + skc];
  const size_t row16 = (size_t)16 * K;

  f32x4 acc[4][4];
  #pragma unroll
  for (int i = 0; i < 4; i++)
    #pragma unroll
    for (int j = 0; j < 4; j++)
      #pragma unroll
      for (int r = 0; r < 4; r++) acc[i][j][r] = 0.f;

  for (int k0 = 0; k0 < K; k0 += 32){
    gload16(Ab + k0,         &As[(w*32     )*32]);
    gload16(Ab + k0 + row16, &As[(w*32 + 16)*32]);
    gload16(Bb + k0,         &Bs[(w*32     )*32]);
    gload16(Bb + k0 + row16, &Bs[(w*32 + 16)*32]);
    __syncthreads();   // compiler emits vmcnt(0) drain before barrier

    bf16x8 af[4], bfv[4];
    #pragma unroll
    for (int mf = 0; mf < 4; mf++)
      af[mf] = *(const bf16x8*)&As[(wm*64 + mf*16 + lrow)*32 + quad*8];
    #pragma unroll
    for (int nf = 0; nf < 4; nf++)
      bfv[nf] = *(const bf16x8*)&Bs[(wn*64 + nf*16 + lrow)*32 + quad*8];
    #pragma unroll
    for (int mf = 0; mf < 4; mf++)
      #pragma unroll
      for (int nf = 0; nf < 4; nf++)
        acc[mf][nf] = __builtin_amdgcn_mfma_f32_16x16x32_bf16(af[mf], bfv[nf], acc[mf][nf], 0, 0, 0);
    __syncthreads();
  }
  #pragma unroll
  for (int mf = 0; mf < 4; mf++){
    #pragma unroll
    for (int nf = 0; nf < 4; nf++){
      int gcol = bN + wn*64 + nf*16 + lrow;
      #pragma unroll
      for (int r = 0; r < 4; r++){
        int grow = bM + wm*64 + mf*16 + quad*4 + r;
        size_t idx = (size_t)grow*N + gcol;
        if constexpr (sizeof(TC) == 4) C[idx] = acc[mf][nf][r];
        else                           C[idx] = f2b(acc[mf][nf][r]);
      }
    }
  }
}

// ---------------- fallback mixed GEMM (harness-verified R0 path) ------------------------
template<typename TA, typename TC>
__global__ __launch_bounds__(256) void gemm_any(const TA* __restrict__ A,
    const float* __restrict__ Bw, TC* __restrict__ C, int M, int N, int K)
{
  __shared__ u16 As[128*40];
  __shared__ u16 Bs[128*40];
  const int tid  = threadIdx.x;
  const int bM   = blockIdx.y * 128;
  const int bN   = blockIdx.x * 128;
  const int lane = tid & 63;
  const int wid  = tid >> 6;
  const int wm   = wid >> 1, wn = wid & 1;
  const int lrow = lane & 15, quad = lane >> 4;

  f32x4 acc[4][4];
  #pragma unroll
  for (int i = 0; i < 4; i++)
    #pragma unroll
    for (int j = 0; j < 4; j++)
      #pragma unroll
      for (int r = 0; r < 4; r++) acc[i][j][r] = 0.f;

  for (int k0 = 0; k0 < K; k0 += 32){
    #pragma unroll
    for (int i = 0; i < 4; i++){
      int c = tid + i*256;
      int row = c >> 3, kc = (c & 7) * 4;
      u16 tmp[4];
      if constexpr (sizeof(TA) == 4){
        float4 v = *(const float4*)&A[(size_t)(bM + row)*K + k0 + kc];
        tmp[0] = f2b(v.x); tmp[1] = f2b(v.y); tmp[2] = f2b(v.z); tmp[3] = f2b(v.w);
      } else {
        *(uint2*)tmp = *(const uint2*)&A[(size_t)(bM + row)*K + k0 + kc];
      }
      *(uint2*)&As[row*40 + kc] = *(uint2*)tmp;
    }
    #pragma unroll
    for (int i = 0; i < 4; i++){
      int c = tid + i*256;
      int kr = c >> 5, nc = (c & 31) * 4;
      float4 v = *(const float4*)&Bw[(size_t)(k0 + kr)*N + bN + nc];
      Bs[(nc+0)*40 + kr] = f2b(v.x);
      Bs[(nc+1)*40 + kr] = f2b(v.y);
      Bs[(nc+2)*40 + kr] = f2b(v.z);
      Bs[(nc+3)*40 + kr] = f2b(v.w);
    }
    __syncthreads();
    bf16x8 af[4], bfv[4];
    #pragma unroll
    for (int mf = 0; mf < 4; mf++)
      af[mf] = *(const bf16x8*)&As[(wm*64 + mf*16 + lrow)*40 + quad*8];
    #pragma unroll
    for (int nf = 0; nf < 4; nf++)
      bfv[nf] = *(const bf16x8*)&Bs[(wn*64 + nf*16 + lrow)*40 + quad*8];
    #pragma unroll
    for (int mf = 0; mf < 4; mf++)
      #pragma unroll
      for (int nf = 0; nf < 4; nf++)
        acc[mf][nf] = __builtin_amdgcn_mfma_f32_16x16x32_bf16(af[mf], bfv[nf], acc[mf][nf], 0, 0, 0);
    __syncthreads();
  }
  #pragma unroll
  for (int mf = 0; mf < 4; mf++){
    #pragma unroll
    for (int nf = 0; nf < 4; nf++){
      int gcol = bN + wn*64 + nf*16 + lrow;
      #pragma unroll
      for (int r = 0; r < 4; r++){
        int grow = bM + wm*64 + mf*16 + quad*4 + r;
        size_t idx = (size_t)grow*N + gcol;
        if constexpr (sizeof(TC) == 4) C[idx] = acc[mf][nf][r];
        else                           C[idx] = f2b(acc[mf][nf][r]);
      }
    }
  }
}

// ---------------- partial interleaved RoPE on q (bf16 ws), in place ---------------------
__global__ void rope_q_kernel(u16* __restrict__ q){
  int gid = blockIdx.x * 256 + threadIdx.x;
  int t = gid >> 9;
  int r = gid & 511;
  int h = r >> 5;
  int i = r & 31;
  int pos = t & (S_LEN - 1);
  float freq = expf(-(float)i * (LN10000 / 32.f));
  float ang = (float)pos * freq;
  float sn, cs;
  sincosf(ang, &sn, &cs);
  size_t off = (size_t)t*HID + h*HD + 64 + 2*i;
  float a  = b2f(q[off]);
  float bb = b2f(q[off+1]);
  q[off]   = f2b(a*cs - bb*sn);
  q[off+1] = f2b(a*sn + bb*cs);
}

// ---------------- overlapped pooling + k RoPE (str-parameterized: 256 split / 512 fused)-
__global__ void pool_rope_k(const u16* __restrict__ kv, const u16* __restrict__ gate,
                            const float* __restrict__ ape, u16* __restrict__ krot,
                            u16* __restrict__ vout, int str){
  const int d = threadIdx.x;   // 0..127
  const int w = blockIdx.x;    // 0..1023
  const int b = blockIdx.y;
  __shared__ float sh[HD];
  const bool hasprev = (w > 0);
  float gc[4], vc[4], gp[4], vp[4];
  float m = NEG_BIG;
  #pragma unroll
  for (int r = 0; r < 4; r++){
    size_t t = (size_t)(b*S_LEN + w*4 + r)*str;
    vc[r] = b2f(kv[t + 128 + d]);
    gc[r] = b2f(gate[t + 128 + d]) + ape[r*256 + 128 + d];
    m = fmaxf(m, gc[r]);
  }
  if (hasprev){
    #pragma unroll
    for (int r = 0; r < 4; r++){
      size_t t = (size_t)(b*S_LEN + (w-1)*4 + r)*str;
      vp[r] = b2f(kv[t + d]);
      gp[r] = b2f(gate[t + d]) + ape[r*256 + d];
      m = fmaxf(m, gp[r]);
    }
  }
  float s = 0.f, acc = 0.f;
  #pragma unroll
  for (int r = 0; r < 4; r++){
    float e = __expf(gc[r] - m); s += e; acc += e*vc[r];
  }
  if (hasprev){
    #pragma unroll
    for (int r = 0; r < 4; r++){
      float e = __expf(gp[r] - m); s += e; acc += e*vp[r];
    }
  }
  float pooled = acc / s;
  sh[d] = pooled;
  __syncthreads();
  float kr = pooled;
  if (d >= 64){
    int i = (d - 64) >> 1;
    float freq = expf(-(float)i * (LN10000 / 32.f));
    float ang = (float)(4*w) * freq;
    float sn, cs;
    sincosf(ang, &sn, &cs);
    if ((d & 1) == 0) kr = sh[d]*cs - sh[d+1]*sn;
    else              kr = sh[d-1]*sn + sh[d]*cs;
  }
  size_t o = (size_t)(b*NW + w)*HD + d;
  krot[o] = f2b(kr);
  vout[o] = f2b(pooled);
}

// ---------------- MFMA flash attention (unchanged from passing R1) ----------------------
#define QT 32
#define KT 64
#define QSTR 136
#define KSTR 136
#define VTSTR 72
#define SSTR 68
#define PSTR 72
#define ATT_SCALE 0.088388347648318447f

__global__ __launch_bounds__(256) void attn_kernel(
    const u16* __restrict__ qbuf, const u16* __restrict__ krot,
    const u16* __restrict__ vbuf, const float* __restrict__ sinks,
    u16* __restrict__ attnbuf)
{
  __shared__ u16 Qs[QT*QSTR];
  __shared__ u16 Ks[KT*KSTR];
  __shared__ u16 Vt[HD*VTSTR];
  __shared__ float Ssc[QT*SSTR];
  __shared__ u16 Ps[QT*PSTR];
  __shared__ float red[256];
  __shared__ float mrow[QT], lrow[QT], arow[QT];

  const int tid  = threadIdx.x;
  const int q0   = blockIdx.x * QT;
  const int h    = blockIdx.y;
  const int b    = blockIdx.z;
  const int lane = tid & 63;
  const int wid  = tid >> 6;
  const int wq   = wid >> 1;
  const int wx   = wid & 1;
  const int lrw  = lane & 15;
  const int quad = lane >> 4;

  #pragma unroll
  for (int i = 0; i < 2; i++){
    int c = tid + i*256;
    int qi = c >> 4, cc = c & 15;
    *(uint4*)&Qs[qi*QSTR + cc*8] =
      *(const uint4*)&qbuf[(size_t)(b*S_LEN + q0 + qi)*HID + h*HD + cc*8];
  }
  if (tid < QT){ mrow[tid] = NEG_BIG; lrow[tid] = 0.f; }

  f32x4 accO[4];
  #pragma unroll
  for (int nf = 0; nf < 4; nf++)
    #pragma unroll
    for (int r = 0; r < 4; r++) accO[nf][r] = 0.f;

  const int kmax_tile = (q0 + QT - 1 - 3) >> 2;
  int nchunk = (kmax_tile >> 6) + 1;
  if (nchunk > NW/KT) nchunk = NW/KT;

  __syncthreads();

  for (int ch = 0; ch < nchunk; ch++){
    const int kc0 = ch * KT;
    #pragma unroll
    for (int i = 0; i < 4; i++){
      int c = tid + i*256;
      int kl = c >> 4, cc = c & 15;
      *(uint4*)&Ks[kl*KSTR + cc*8] =
        *(const uint4*)&krot[(size_t)(b*NW + kc0 + kl)*HD + cc*8];
    }
    {
      int kl = tid & 63;
      int dbase = (tid >> 6) * 8;
      #pragma unroll
      for (int i = 0; i < 4; i++){
        int d0 = dbase + i*32;
        u16 tmp[8];
        *(uint4*)tmp = *(const uint4*)&vbuf[(size_t)(b*NW + kc0 + kl)*HD + d0];
        #pragma unroll
        for (int j = 0; j < 8; j++) Vt[(d0+j)*VTSTR + kl] = tmp[j];
      }
    }
    __syncthreads();

    f32x4 accS[2];
    #pragma unroll
    for (int nf = 0; nf < 2; nf++)
      #pragma unroll
      for (int r = 0; r < 4; r++) accS[nf][r] = 0.f;
    #pragma unroll
    for (int d0 = 0; d0 < HD; d0 += 32){
      bf16x8 af = *(const bf16x8*)&Qs[(wq*16 + lrw)*QSTR + d0 + quad*8];
      #pragma unroll
      for (int nf = 0; nf < 2; nf++){
        bf16x8 bf = *(const bf16x8*)&Ks[(wx*32 + nf*16 + lrw)*KSTR + d0 + quad*8];
        accS[nf] = __builtin_amdgcn_mfma_f32_16x16x32_bf16(af, bf, accS[nf], 0, 0, 0);
      }
    }
    #pragma unroll
    for (int nf = 0; nf < 2; nf++)
      #pragma unroll
      for (int r = 0; r < 4; r++)
        Ssc[(wq*16 + quad*4 + r)*SSTR + wx*32 + nf*16 + lrw] = accS[nf][r];
    __syncthreads();

    const int sqi = tid >> 3;
    const int seg = (tid & 7) * 8;
    const int qg  = q0 + sqi;
    float sv[8];
    float lmax = NEG_BIG;
    #pragma unroll
    for (int j = 0; j < 8; j++){
      int kg = kc0 + seg + j;
      float s = Ssc[sqi*SSTR + seg + j];
      s = (qg >= 4*kg + 3) ? s*ATT_SCALE : NEG_BIG;
      sv[j] = s;
      lmax = fmaxf(lmax, s);
    }
    red[tid] = lmax;
    __syncthreads();
    if (tid < QT){
      float mold = mrow[tid];
      float mx = mold;
      #pragma unroll
      for (int j = 0; j < 8; j++) mx = fmaxf(mx, red[tid*8 + j]);
      arow[tid] = __expf(mold - mx);
      mrow[tid] = mx;
    }
    __syncthreads();
    {
      float mloc = mrow[sqi];
      float ps = 0.f;
      u16 pb[8];
      #pragma unroll
      for (int j = 0; j < 8; j++){
        float p = __expf(sv[j] - mloc);
        ps += p;
        pb[j] = f2b(p);
      }
      *(uint4*)&Ps[sqi*PSTR + seg] = *(uint4*)pb;
      red[tid] = ps;
    }
    __syncthreads();
    if (tid < QT){
      float sum = 0.f;
      #pragma unroll
      for (int j = 0; j < 8; j++) sum += red[tid*8 + j];
      lrow[tid] = lrow[tid]*arow[tid] + sum;
    }
    {
      float al[4];
      #pragma unroll
      for (int r = 0; r < 4; r++) al[r] = arow[wq*16 + quad*4 + r];
      #pragma unroll
      for (int nf = 0; nf < 4; nf++)
        #pragma unroll
        for (int r = 0; r < 4; r++) accO[nf][r] *= al[r];
      #pragma unroll
      for (int kk = 0; kk < KT; kk += 32){
        bf16x8 paf = *(const bf16x8*)&Ps[(wq*16 + lrw)*PSTR + kk + quad*8];
        #pragma unroll
        for (int nf = 0; nf < 4; nf++){
          bf16x8 vbf = *(const bf16x8*)&Vt[(wx*64 + nf*16 + lrw)*VTSTR + kk + quad*8];
          accO[nf] = __builtin_amdgcn_mfma_f32_16x16x32_bf16(paf, vbf, accO[nf], 0, 0, 0);
        }
      }
    }
    __syncthreads();
  }

  const float snk = sinks[h];
  #pragma unroll
  for (int r = 0; r < 4; r++){
    int q = wq*16 + quad*4 + r;
    float m = mrow[q], l = lrow[q];
    float mf = fmaxf(m, snk);
    float em = __expf(m - mf);
    float sc = em / (l*em + __expf(snk - mf));
    size_t o = (size_t)(b*S_LEN + q0 + q)*HID + h*HD + wx*64 + lrw;
    #pragma unroll
    for (int nf = 0; nf < 4; nf++)
      attnbuf[o + nf*16] = f2b(accO[nf][r] * sc);
  }
}

// ---------------------------------------------------------------------------------------
extern "C" void kernel_launch(void* const* d_in, const int* in_sizes, int n_in,
                              void* d_out, int out_size, void* d_ws, size_t ws_size,
                              hipStream_t stream)
{
  const float* hidden = (const float*)d_in[0];
  const float* wq     = (const float*)d_in[1];
  const float* wkv    = (const float*)d_in[2];
  const float* wgate  = (const float*)d_in[3];
  const float* ape    = (const float*)d_in[4];
  const float* sinks  = (const float*)d_in[5];
  const float* wo     = (const float*)d_in[6];

  // new-path workspace (u16 units); attnbuf aliases hid_bf (dead after kvg GEMM),
  // woT aliases kvg (dead after pool_rope_k, exact 4.19M-u16 fit)
  const size_t NEED = ((size_t)TOK*HID*2 + (size_t)TOK*512 + (size_t)4*NW*HD
                     + (size_t)HID*HID + (size_t)512*HID) * sizeof(u16); // 87.0 MB

  if (ws_size >= NEED){
    u16* hid_bf = (u16*)d_ws;                         // TOK*HID       (also attnbuf)
    u16* qbuf   = hid_bf + (size_t)TOK*HID;           // TOK*HID
    u16* kvg    = qbuf   + (size_t)TOK*HID;           // TOK*512       (also woT)
    u16* krot   = kvg    + (size_t)TOK*512;           // 2*NW*HD
    u16* vbuf   = krot   + (size_t)2*NW*HD;           // 2*NW*HD
    u16* wqT    = vbuf   + (size_t)2*NW*HD;           // 2048*2048
    u16* wkvgT  = wqT    + (size_t)HID*HID;           // 512*2048
    u16* attnbuf = hid_bf;
    u16* woT     = kvg;

    cvt_bf16<<<(TOK*HID/8)/256, 256, 0, stream>>>(hidden, hid_bf);
    transpose_w<<<dim3(HID/32, HID/32), 256, 0, stream>>>(wq, wqT, HID, HID);
    transpose_w<<<dim3(256/32, HID/32), 256, 0, stream>>>(wkv,   wkvgT,            HID, 256);
    transpose_w<<<dim3(256/32, HID/32), 256, 0, stream>>>(wgate, wkvgT + (size_t)256*HID, HID, 256);
    gemm_bf16<u16><<<dim3(HID/128, TOK/128), 256, 0, stream>>>(hid_bf, wqT,   qbuf, TOK, HID, HID);
    gemm_bf16<u16><<<dim3(512/128, TOK/128), 256, 0, stream>>>(hid_bf, wkvgT, kvg,  TOK, 512, HID);
    rope_q_kernel<<<(TOK*NHEAD*32)/256, 256, 0, stream>>>(qbuf);
    pool_rope_k<<<dim3(NW, 2), 128, 0, stream>>>(kvg, kvg + 256, ape, krot, vbuf, 512);
    attn_kernel<<<dim3(S_LEN/QT, NHEAD, 2), 256, 0, stream>>>(qbuf, krot, vbuf, sinks, attnbuf);
    transpose_w<<<dim3(HID/32, HID/32), 256, 0, stream>>>(wo, woT, HID, HID);   // kvg dead
    gemm_bf16<float><<<dim3(HID/128, TOK/128), 256, 0, stream>>>(attnbuf, woT, (float*)d_out, TOK, HID, HID);
  } else {
    // fallback: R0 verified path (76.6 MB)
    u16* qbuf    = (u16*)d_ws;
    u16* kvbuf   = qbuf    + (size_t)TOK*HID;
    u16* gatebuf = kvbuf   + (size_t)TOK*256;
    u16* krot    = gatebuf + (size_t)TOK*256;
    u16* vbuf    = krot    + (size_t)2*NW*HD;
    u16* attnbuf = vbuf    + (size_t)2*NW*HD;

    gemm_any<float,u16><<<dim3(HID/128, TOK/128), 256, 0, stream>>>(hidden, wq,    qbuf,    TOK, HID, HID);
    gemm_any<float,u16><<<dim3(256/128, TOK/128), 256, 0, stream>>>(hidden, wkv,   kvbuf,   TOK, 256, HID);
    gemm_any<float,u16><<<dim3(256/128, TOK/128), 256, 0, stream>>>(hidden, wgate, gatebuf, TOK, 256, HID);
    rope_q_kernel<<<(TOK*NHEAD*32)/256, 256, 0, stream>>>(qbuf);
    pool_rope_k<<<dim3(NW, 2), 128, 0, stream>>>(kvbuf, gatebuf, ape, krot, vbuf, 256);
    attn_kernel<<<dim3(S_LEN/QT, NHEAD, 2), 256, 0, stream>>>(qbuf, krot, vbuf, sinks, attnbuf);
    gemm_any<u16,float><<<dim3(HID/128, TOK/128), 256, 0, stream>>>(attnbuf, wo, (float*)d_out, TOK, HID, HID);
  }
}

// Round 3
// 557.351 us; speedup vs baseline: 3.9246x; 1.1336x over previous
//
#include <hip/hip_runtime.h>
#include <math.h>

typedef unsigned short u16;
typedef unsigned int   u32;
typedef __bf16 bf16x8 __attribute__((ext_vector_type(8)));
typedef float  f32x4  __attribute__((ext_vector_type(4)));

#define S_LEN 4096
#define HID   2048
#define NHEAD 16
#define HD    128
#define NW    1024
#define TOK   8192
#define LN10000 9.2103403719761836f
#define NEG_BIG (-1e30f)

__device__ __forceinline__ float b2f(u16 u){
  union { u32 i; float f; } v; v.i = ((u32)u) << 16; return v.f;
}
__device__ __forceinline__ u16 f2b(float f){
  union { float f; u32 i; } v; v.f = f;
  return (u16)((v.i + 0x7FFFu + ((v.i >> 16) & 1u)) >> 16);
}

// ---------------- one-time f32 -> bf16 convert (hidden), 8 elems/thread -----------------
__global__ __launch_bounds__(256) void cvt_bf16(const float* __restrict__ in,
                                                u16* __restrict__ out){
  size_t i = (size_t)blockIdx.x*256 + threadIdx.x;
  float4 a = ((const float4*)in)[2*i];
  float4 b = ((const float4*)in)[2*i+1];
  u16 t[8];
  t[0]=f2b(a.x); t[1]=f2b(a.y); t[2]=f2b(a.z); t[3]=f2b(a.w);
  t[4]=f2b(b.x); t[5]=f2b(b.y); t[6]=f2b(b.z); t[7]=f2b(b.w);
  *(uint4*)&out[i*8] = *(uint4*)t;
}

// ---------------- one-time weight transpose+convert: f32[K][N] -> bf16[N][K] ------------
__global__ __launch_bounds__(256) void transpose_w(const float* __restrict__ in,
    u16* __restrict__ out, int K, int N){
  __shared__ float t[32][33];
  const int n0 = blockIdx.x*32, k0 = blockIdx.y*32;
  const int c = threadIdx.x & 31, r8 = threadIdx.x >> 5;
  #pragma unroll
  for (int i = 0; i < 4; i++)
    t[r8 + i*8][c] = in[(size_t)(k0 + r8 + i*8)*N + n0 + c];
  __syncthreads();
  #pragma unroll
  for (int i = 0; i < 4; i++)
    out[(size_t)(n0 + r8 + i*8)*K + k0 + c] = f2b(t[c][r8 + i*8]);
}

// ---------------- m97-structure bf16 GEMM: C(M,N) = A(M,K) @ Bt(N,K)^T ------------------
typedef __attribute__((address_space(3))) u16 as3_u16;
typedef __attribute__((address_space(1))) const u16 as1_u16;
__device__ __forceinline__ void gload16(const u16* g, u16* l){
  __builtin_amdgcn_global_load_lds((as1_u16*)g, (as3_u16*)l, 16, 0, 0);
}

template<typename TC>
__global__ __launch_bounds__(256) void gemm_bf16(const u16* __restrict__ A,
    const u16* __restrict__ Bt, TC* __restrict__ C, int M, int N, int K)
{
  __shared__ u16 As[128*32];
  __shared__ u16 Bs[128*32];
  const int tid  = threadIdx.x;
  const int bM   = blockIdx.y * 128;
  const int bN   = blockIdx.x * 128;
  const int lane = tid & 63;
  const int w    = tid >> 6;
  const int wm   = w >> 1, wn = w & 1;
  const int lrow = lane & 15, quad = lane >> 4;
  const int srow = lane >> 2, skc = (lane & 3) * 8;

  const u16* Ab = &A [(size_t)(bM + w*32 + srow)*K + skc];
  const u16* Bb = &Bt[(size_t)(bN + w*32 + srow)*K + skc];
  const size_t row16 = (size_t)16 * K;

  f32x4 acc[4][4];
  #pragma unroll
  for (int i = 0; i < 4; i++)
    #pragma unroll
    for (int j = 0; j < 4; j++)
      #pragma unroll
      for (int r = 0; r < 4; r++) acc[i][j][r] = 0.f;

  for (int k0 = 0; k0 < K; k0 += 32){
    gload16(Ab + k0,         &As[(w*32     )*32]);
    gload16(Ab + k0 + row16, &As[(w*32 + 16)*32]);
    gload16(Bb + k0,         &Bs[(w*32     )*32]);
    gload16(Bb + k0 + row16, &Bs[(w*32 + 16)*32]);
    __syncthreads();

    bf16x8 af[4], bfv[4];
    #pragma unroll
    for (int mf = 0; mf < 4; mf++)
      af[mf] = *(const bf16x8*)&As[(wm*64 + mf*16 + lrow)*32 + quad*8];
    #pragma unroll
    for (int nf = 0; nf < 4; nf++)
      bfv[nf] = *(const bf16x8*)&Bs[(wn*64 + nf*16 + lrow)*32 + quad*8];
    #pragma unroll
    for (int mf = 0; mf < 4; mf++)
      #pragma unroll
      for (int nf = 0; nf < 4; nf++)
        acc[mf][nf] = __builtin_amdgcn_mfma_f32_16x16x32_bf16(af[mf], bfv[nf], acc[mf][nf], 0, 0, 0);
    __syncthreads();
  }
  #pragma unroll
  for (int mf = 0; mf < 4; mf++){
    #pragma unroll
    for (int nf = 0; nf < 4; nf++){
      int gcol = bN + wn*64 + nf*16 + lrow;
      #pragma unroll
      for (int r = 0; r < 4; r++){
        int grow = bM + wm*64 + mf*16 + quad*4 + r;
        size_t idx = (size_t)grow*N + gcol;
        if constexpr (sizeof(TC) == 4) C[idx] = acc[mf][nf][r];
        else                           C[idx] = f2b(acc[mf][nf][r]);
      }
    }
  }
}

// ---------------- fallback mixed GEMM (harness-verified R0 path) ------------------------
template<typename TA, typename TC>
__global__ __launch_bounds__(256) void gemm_any(const TA* __restrict__ A,
    const float* __restrict__ Bw, TC* __restrict__ C, int M, int N, int K)
{
  __shared__ u16 As[128*40];
  __shared__ u16 Bs[128*40];
  const int tid  = threadIdx.x;
  const int bM   = blockIdx.y * 128;
  const int bN   = blockIdx.x * 128;
  const int lane = tid & 63;
  const int wid  = tid >> 6;
  const int wm   = wid >> 1, wn = wid & 1;
  const int lrow = lane & 15, quad = lane >> 4;

  f32x4 acc[4][4];
  #pragma unroll
  for (int i = 0; i < 4; i++)
    #pragma unroll
    for (int j = 0; j < 4; j++)
      #pragma unroll
      for (int r = 0; r < 4; r++) acc[i][j][r] = 0.f;

  for (int k0 = 0; k0 < K; k0 += 32){
    #pragma unroll
    for (int i = 0; i < 4; i++){
      int c = tid + i*256;
      int row = c >> 3, kc = (c & 7) * 4;
      u16 tmp[4];
      if constexpr (sizeof(TA) == 4){
        float4 v = *(const float4*)&A[(size_t)(bM + row)*K + k0 + kc];
        tmp[0] = f2b(v.x); tmp[1] = f2b(v.y); tmp[2] = f2b(v.z); tmp[3] = f2b(v.w);
      } else {
        *(uint2*)tmp = *(const uint2*)&A[(size_t)(bM + row)*K + k0 + kc];
      }
      *(uint2*)&As[row*40 + kc] = *(uint2*)tmp;
    }
    #pragma unroll
    for (int i = 0; i < 4; i++){
      int c = tid + i*256;
      int kr = c >> 5, nc = (c & 31) * 4;
      float4 v = *(const float4*)&Bw[(size_t)(k0 + kr)*N + bN + nc];
      Bs[(nc+0)*40 + kr] = f2b(v.x);
      Bs[(nc+1)*40 + kr] = f2b(v.y);
      Bs[(nc+2)*40 + kr] = f2b(v.z);
      Bs[(nc+3)*40 + kr] = f2b(v.w);
    }
    __syncthreads();
    bf16x8 af[4], bfv[4];
    #pragma unroll
    for (int mf = 0; mf < 4; mf++)
      af[mf] = *(const bf16x8*)&As[(wm*64 + mf*16 + lrow)*40 + quad*8];
    #pragma unroll
    for (int nf = 0; nf < 4; nf++)
      bfv[nf] = *(const bf16x8*)&Bs[(wn*64 + nf*16 + lrow)*40 + quad*8];
    #pragma unroll
    for (int mf = 0; mf < 4; mf++)
      #pragma unroll
      for (int nf = 0; nf < 4; nf++)
        acc[mf][nf] = __builtin_amdgcn_mfma_f32_16x16x32_bf16(af[mf], bfv[nf], acc[mf][nf], 0, 0, 0);
    __syncthreads();
  }
  #pragma unroll
  for (int mf = 0; mf < 4; mf++){
    #pragma unroll
    for (int nf = 0; nf < 4; nf++){
      int gcol = bN + wn*64 + nf*16 + lrow;
      #pragma unroll
      for (int r = 0; r < 4; r++){
        int grow = bM + wm*64 + mf*16 + quad*4 + r;
        size_t idx = (size_t)grow*N + gcol;
        if constexpr (sizeof(TC) == 4) C[idx] = acc[mf][nf][r];
        else                           C[idx] = f2b(acc[mf][nf][r]);
      }
    }
  }
}

// ---------------- partial interleaved RoPE on q (bf16 ws), in place ---------------------
__global__ void rope_q_kernel(u16* __restrict__ q){
  int gid = blockIdx.x * 256 + threadIdx.x;
  int t = gid >> 9;
  int r = gid & 511;
  int h = r >> 5;
  int i = r & 31;
  int pos = t & (S_LEN - 1);
  float freq = expf(-(float)i * (LN10000 / 32.f));
  float ang = (float)pos * freq;
  float sn, cs;
  sincosf(ang, &sn, &cs);
  size_t off = (size_t)t*HID + h*HD + 64 + 2*i;
  float a  = b2f(q[off]);
  float bb = b2f(q[off+1]);
  q[off]   = f2b(a*cs - bb*sn);
  q[off+1] = f2b(a*sn + bb*cs);
}

// ---------------- overlapped pooling + k RoPE (str: 256 split / 512 fused) --------------
__global__ void pool_rope_k(const u16* __restrict__ kv, const u16* __restrict__ gate,
                            const float* __restrict__ ape, u16* __restrict__ krot,
                            u16* __restrict__ vout, int str){
  const int d = threadIdx.x;   // 0..127
  const int w = blockIdx.x;    // 0..1023
  const int b = blockIdx.y;
  __shared__ float sh[HD];
  const bool hasprev = (w > 0);
  float gc[4], vc[4], gp[4], vp[4];
  float m = NEG_BIG;
  #pragma unroll
  for (int r = 0; r < 4; r++){
    size_t t = (size_t)(b*S_LEN + w*4 + r)*str;
    vc[r] = b2f(kv[t + 128 + d]);
    gc[r] = b2f(gate[t + 128 + d]) + ape[r*256 + 128 + d];
    m = fmaxf(m, gc[r]);
  }
  if (hasprev){
    #pragma unroll
    for (int r = 0; r < 4; r++){
      size_t t = (size_t)(b*S_LEN + (w-1)*4 + r)*str;
      vp[r] = b2f(kv[t + d]);
      gp[r] = b2f(gate[t + d]) + ape[r*256 + d];
      m = fmaxf(m, gp[r]);
    }
  }
  float s = 0.f, acc = 0.f;
  #pragma unroll
  for (int r = 0; r < 4; r++){
    float e = __expf(gc[r] - m); s += e; acc += e*vc[r];
  }
  if (hasprev){
    #pragma unroll
    for (int r = 0; r < 4; r++){
      float e = __expf(gp[r] - m); s += e; acc += e*vp[r];
    }
  }
  float pooled = acc / s;
  sh[d] = pooled;
  __syncthreads();
  float kr = pooled;
  if (d >= 64){
    int i = (d - 64) >> 1;
    float freq = expf(-(float)i * (LN10000 / 32.f));
    float ang = (float)(4*w) * freq;
    float sn, cs;
    sincosf(ang, &sn, &cs);
    if ((d & 1) == 0) kr = sh[d]*cs - sh[d+1]*sn;
    else              kr = sh[d-1]*sn + sh[d]*cs;
  }
  size_t o = (size_t)(b*NW + w)*HD + d;
  krot[o] = f2b(kr);
  vout[o] = f2b(pooled);
}

// ---------------- MFMA flash attention, swapped operands (register softmax) -------------
// QT=64, 4 waves; wave w owns q-rows [q0+w*16, +16), full 128-d output. Both MFMAs are
// operand-swapped so q is the MFMA *column* (= lane&15): softmax stats (m,l,alpha) are
// per-lane scalars, row-reduce = 2 shfl_xor (quads hold disjoint k). Per chunk: 2 barriers
// (K/V stage in/out); P goes through a per-wave LDS strip (wave-synchronous, no barrier).
// Q lives in 4 bf16x8 regs. Layouts (m89/m91): A-frag lane=(A[m=lane&15][k=quad*8+j]),
// B-frag same with n=lane&15; C/D col=lane&15, row=quad*4+reg. All LDS strides chosen so
// quarter-wave b128/b64 access is 2-way (free, m136). Fully-masked rows (qg<3): p==1
// garbage, killed by sc==0 in the sink epilogue (verified self-healing).
#define AQT 64
#define AKT 64
#define AKSTR 136  // u16: 272B rows, frag reads 2-way
#define AVSTR 72   // u16: 144B rows
#define APSTR 72
#define ATT_SCALE 0.088388347648318447f

__global__ __launch_bounds__(256, 3) void attn_kernel(
    const u16* __restrict__ qbuf, const u16* __restrict__ krot,
    const u16* __restrict__ vbuf, const float* __restrict__ sinks,
    u16* __restrict__ attnbuf)
{
  __shared__ u16 Ks[AKT*AKSTR];   // [k][d]   17408 B
  __shared__ u16 Vt[HD*AVSTR];    // [dv][k]  18432 B
  __shared__ u16 Pq[AQT*APSTR];   // per-wave [q][k] strips, 9216 B

  const int tid  = threadIdx.x;
  const int q0   = blockIdx.x * AQT;
  const int h    = blockIdx.y;
  const int b    = blockIdx.z;
  const int lane = tid & 63;
  const int wq   = tid >> 6;
  const int lrw  = lane & 15;
  const int quad = lane >> 4;
  const int qg   = q0 + wq*16 + lrw;   // this lane's q-row

  // Q fragments in registers (B-operand layout: n=lrw, k=d0*32+quad*8+j)
  bf16x8 qf[4];
  {
    const u16* qrow = &qbuf[(size_t)(b*S_LEN + qg)*HID + h*HD];
    #pragma unroll
    for (int d0 = 0; d0 < 4; d0++)
      qf[d0] = *(const bf16x8*)&qrow[d0*32 + quad*8];
  }

  float m_run = NEG_BIG, l_run = 0.f;
  f32x4 accO[8];
  #pragma unroll
  for (int ds = 0; ds < 8; ds++)
    #pragma unroll
    for (int r = 0; r < 4; r++) accO[ds][r] = 0.f;

  const int kmax_tile = (q0 + AQT - 1 - 3) >> 2;
  int nchunk = (kmax_tile >> 6) + 1;
  if (nchunk > NW/AKT) nchunk = NW/AKT;

  for (int ch = 0; ch < nchunk; ch++){
    const int kc0 = ch * AKT;
    // stage K natural [k][d]: 1024 uint4 / 256 thr
    #pragma unroll
    for (int i = 0; i < 4; i++){
      int c = tid + i*256;
      int kl = c >> 4, cc = c & 15;
      *(uint4*)&Ks[kl*AKSTR + cc*8] =
        *(const uint4*)&krot[(size_t)(b*NW + kc0 + kl)*HD + cc*8];
    }
    // stage V transposed Vt[dv][k]
    {
      int kl = tid & 63;
      int dbase = (tid >> 6) * 8;
      #pragma unroll
      for (int i = 0; i < 4; i++){
        int d0 = dbase + i*32;
        u16 tmp[8];
        *(uint4*)tmp = *(const uint4*)&vbuf[(size_t)(b*NW + kc0 + kl)*HD + d0];
        #pragma unroll
        for (int j = 0; j < 8; j++) Vt[(d0+j)*AVSTR + kl] = tmp[j];
      }
    }
    __syncthreads();

    // QK^T swapped: St[k][q] — lane gets k=ks*16+quad*4+r for its q=lrw
    f32x4 accS[4];
    #pragma unroll
    for (int ks = 0; ks < 4; ks++)
      #pragma unroll
      for (int r = 0; r < 4; r++) accS[ks][r] = 0.f;
    #pragma unroll
    for (int d0 = 0; d0 < 4; d0++){
      #pragma unroll
      for (int ks = 0; ks < 4; ks++){
        bf16x8 af = *(const bf16x8*)&Ks[(ks*16 + lrw)*AKSTR + d0*32 + quad*8];
        accS[ks] = __builtin_amdgcn_mfma_f32_16x16x32_bf16(af, qf[d0], accS[ks], 0, 0, 0);
      }
    }

    // register softmax: mask+scale, row-reduce via shfl_xor over quads
    float p[16];
    float lmax = NEG_BIG;
    #pragma unroll
    for (int ks = 0; ks < 4; ks++)
      #pragma unroll
      for (int r = 0; r < 4; r++){
        int kg = kc0 + ks*16 + quad*4 + r;
        float s = (qg >= 4*kg + 3) ? accS[ks][r]*ATT_SCALE : NEG_BIG;
        p[ks*4 + r] = s;
        lmax = fmaxf(lmax, s);
      }
    lmax = fmaxf(lmax, __shfl_xor(lmax, 16));
    lmax = fmaxf(lmax, __shfl_xor(lmax, 32));
    float mnew  = fmaxf(m_run, lmax);
    float alpha = __expf(m_run - mnew);
    m_run = mnew;
    float ls = 0.f;
    #pragma unroll
    for (int i = 0; i < 16; i++){
      float e = __expf(p[i] - mnew);
      p[i] = e; ls += e;
    }
    ls += __shfl_xor(ls, 16);
    ls += __shfl_xor(ls, 32);
    l_run = l_run*alpha + ls;

    // P -> per-wave LDS strip (wave-synchronous; no barrier needed)
    #pragma unroll
    for (int ks = 0; ks < 4; ks++){
      u16 pb[4];
      #pragma unroll
      for (int r = 0; r < 4; r++) pb[r] = f2b(p[ks*4 + r]);
      *(uint2*)&Pq[(wq*16 + lrw)*APSTR + ks*16 + quad*4] = *(uint2*)pb;
    }

    // rescale O^T (alpha is lane-local: accO col = q = lrw)
    #pragma unroll
    for (int ds = 0; ds < 8; ds++)
      #pragma unroll
      for (int r = 0; r < 4; r++) accO[ds][r] *= alpha;

    // PV swapped: O^T[dv][q] += Vt[dv][k] * P^T[k][q]
    #pragma unroll
    for (int kks = 0; kks < 2; kks++){
      bf16x8 pf = *(const bf16x8*)&Pq[(wq*16 + lrw)*APSTR + kks*32 + quad*8];
      #pragma unroll
      for (int ds = 0; ds < 8; ds++){
        bf16x8 av = *(const bf16x8*)&Vt[(ds*16 + lrw)*AVSTR + kks*32 + quad*8];
        accO[ds] = __builtin_amdgcn_mfma_f32_16x16x32_bf16(av, pf, accO[ds], 0, 0, 0);
      }
    }
    __syncthreads();   // protect Ks/Vt for next chunk's staging
  }

  // sink epilogue (per-lane; quads hold disjoint dv quarters of row q)
  const float snk = sinks[h];
  float mf = fmaxf(m_run, snk);
  float em = __expf(m_run - mf);
  float sc = em / (l_run*em + __expf(snk - mf));
  size_t o = (size_t)(b*S_LEN + qg)*HID + h*HD;
  #pragma unroll
  for (int ds = 0; ds < 8; ds++){
    u16 ob[4];
    #pragma unroll
    for (int r = 0; r < 4; r++) ob[r] = f2b(accO[ds][r] * sc);
    *(uint2*)&attnbuf[o + ds*16 + quad*4] = *(uint2*)ob;
  }
}

// ---------------------------------------------------------------------------------------
extern "C" void kernel_launch(void* const* d_in, const int* in_sizes, int n_in,
                              void* d_out, int out_size, void* d_ws, size_t ws_size,
                              hipStream_t stream)
{
  const float* hidden = (const float*)d_in[0];
  const float* wq     = (const float*)d_in[1];
  const float* wkv    = (const float*)d_in[2];
  const float* wgate  = (const float*)d_in[3];
  const float* ape    = (const float*)d_in[4];
  const float* sinks  = (const float*)d_in[5];
  const float* wo     = (const float*)d_in[6];

  const size_t NEED = ((size_t)TOK*HID*2 + (size_t)TOK*512 + (size_t)4*NW*HD
                     + (size_t)HID*HID + (size_t)512*HID) * sizeof(u16); // 87.0 MB

  if (ws_size >= NEED){
    u16* hid_bf = (u16*)d_ws;                         // TOK*HID       (also attnbuf)
    u16* qbuf   = hid_bf + (size_t)TOK*HID;           // TOK*HID
    u16* kvg    = qbuf   + (size_t)TOK*HID;           // TOK*512       (also woT)
    u16* krot   = kvg    + (size_t)TOK*512;           // 2*NW*HD
    u16* vbuf   = krot   + (size_t)2*NW*HD;           // 2*NW*HD
    u16* wqT    = vbuf   + (size_t)2*NW*HD;           // 2048*2048
    u16* wkvgT  = wqT    + (size_t)HID*HID;           // 512*2048
    u16* attnbuf = hid_bf;
    u16* woT     = kvg;

    cvt_bf16<<<(TOK*HID/8)/256, 256, 0, stream>>>(hidden, hid_bf);
    transpose_w<<<dim3(HID/32, HID/32), 256, 0, stream>>>(wq, wqT, HID, HID);
    transpose_w<<<dim3(256/32, HID/32), 256, 0, stream>>>(wkv,   wkvgT,            HID, 256);
    transpose_w<<<dim3(256/32, HID/32), 256, 0, stream>>>(wgate, wkvgT + (size_t)256*HID, HID, 256);
    gemm_bf16<u16><<<dim3(HID/128, TOK/128), 256, 0, stream>>>(hid_bf, wqT,   qbuf, TOK, HID, HID);
    gemm_bf16<u16><<<dim3(512/128, TOK/128), 256, 0, stream>>>(hid_bf, wkvgT, kvg,  TOK, 512, HID);
    rope_q_kernel<<<(TOK*NHEAD*32)/256, 256, 0, stream>>>(qbuf);
    pool_rope_k<<<dim3(NW, 2), 128, 0, stream>>>(kvg, kvg + 256, ape, krot, vbuf, 512);
    attn_kernel<<<dim3(S_LEN/AQT, NHEAD, 2), 256, 0, stream>>>(qbuf, krot, vbuf, sinks, attnbuf);
    transpose_w<<<dim3(HID/32, HID/32), 256, 0, stream>>>(wo, woT, HID, HID);   // kvg dead
    gemm_bf16<float><<<dim3(HID/128, TOK/128), 256, 0, stream>>>(attnbuf, woT, (float*)d_out, TOK, HID, HID);
  } else {
    // fallback: R0 verified path (76.6 MB)
    u16* qbuf    = (u16*)d_ws;
    u16* kvbuf   = qbuf    + (size_t)TOK*HID;
    u16* gatebuf = kvbuf   + (size_t)TOK*256;
    u16* krot    = gatebuf + (size_t)TOK*256;
    u16* vbuf    = krot    + (size_t)2*NW*HD;
    u16* attnbuf = vbuf    + (size_t)2*NW*HD;

    gemm_any<float,u16><<<dim3(HID/128, TOK/128), 256, 0, stream>>>(hidden, wq,    qbuf,    TOK, HID, HID);
    gemm_any<float,u16><<<dim3(256/128, TOK/128), 256, 0, stream>>>(hidden, wkv,   kvbuf,   TOK, 256, HID);
    gemm_any<float,u16><<<dim3(256/128, TOK/128), 256, 0, stream>>>(hidden, wgate, gatebuf, TOK, 256, HID);
    rope_q_kernel<<<(TOK*NHEAD*32)/256, 256, 0, stream>>>(qbuf);
    pool_rope_k<<<dim3(NW, 2), 128, 0, stream>>>(kvbuf, gatebuf, ape, krot, vbuf, 256);
    attn_kernel<<<dim3(S_LEN/AQT, NHEAD, 2), 256, 0, stream>>>(qbuf, krot, vbuf, sinks, attnbuf);
    gemm_any<u16,float><<<dim3(HID/128, TOK/128), 256, 0, stream>>>(attnbuf, wo, (float*)d_out, TOK, HID, HID);
  }
}

// Round 4
// 546.411 us; speedup vs baseline: 4.0032x; 1.0200x over previous
//
#include <hip/hip_runtime.h>
#include <math.h>

typedef unsigned short u16;
typedef unsigned int   u32;
typedef __bf16 bf16x8 __attribute__((ext_vector_type(8)));
typedef float  f32x4  __attribute__((ext_vector_type(4)));

#define S_LEN 4096
#define HID   2048
#define NHEAD 16
#define HD    128
#define NW    1024
#define TOK   8192
#define LN10000 9.2103403719761836f
#define NEG_BIG (-1e30f)

__device__ __forceinline__ float b2f(u16 u){
  union { u32 i; float f; } v; v.i = ((u32)u) << 16; return v.f;
}
__device__ __forceinline__ u16 f2b(float f){
  union { float f; u32 i; } v; v.f = f;
  return (u16)((v.i + 0x7FFFu + ((v.i >> 16) & 1u)) >> 16);
}

// ---------------- one-time f32 -> bf16 convert (hidden), 8 elems/thread -----------------
__global__ __launch_bounds__(256) void cvt_bf16(const float* __restrict__ in,
                                                u16* __restrict__ out){
  size_t i = (size_t)blockIdx.x*256 + threadIdx.x;
  float4 a = ((const float4*)in)[2*i];
  float4 b = ((const float4*)in)[2*i+1];
  u16 t[8];
  t[0]=f2b(a.x); t[1]=f2b(a.y); t[2]=f2b(a.z); t[3]=f2b(a.w);
  t[4]=f2b(b.x); t[5]=f2b(b.y); t[6]=f2b(b.z); t[7]=f2b(b.w);
  *(uint4*)&out[i*8] = *(uint4*)t;
}

// ---------------- one-time weight transpose+convert: f32[K][N] -> bf16[N][K] ------------
__global__ __launch_bounds__(256) void transpose_w(const float* __restrict__ in,
    u16* __restrict__ out, int K, int N){
  __shared__ float t[32][33];
  const int n0 = blockIdx.x*32, k0 = blockIdx.y*32;
  const int c = threadIdx.x & 31, r8 = threadIdx.x >> 5;
  #pragma unroll
  for (int i = 0; i < 4; i++)
    t[r8 + i*8][c] = in[(size_t)(k0 + r8 + i*8)*N + n0 + c];
  __syncthreads();
  #pragma unroll
  for (int i = 0; i < 4; i++)
    out[(size_t)(n0 + r8 + i*8)*K + k0 + c] = f2b(t[c][r8 + i*8]);
}

// ---------------- m97-structure bf16 GEMM: C(M,N) = A(M,K) @ Bt(N,K)^T ------------------
typedef __attribute__((address_space(3))) u16 as3_u16;
typedef __attribute__((address_space(1))) const u16 as1_u16;
__device__ __forceinline__ void gload16(const u16* g, u16* l){
  __builtin_amdgcn_global_load_lds((as1_u16*)g, (as3_u16*)l, 16, 0, 0);
}

template<typename TC>
__global__ __launch_bounds__(256) void gemm_bf16(const u16* __restrict__ A,
    const u16* __restrict__ Bt, TC* __restrict__ C, int M, int N, int K)
{
  __shared__ u16 As[128*32];
  __shared__ u16 Bs[128*32];
  const int tid  = threadIdx.x;
  const int bM   = blockIdx.y * 128;
  const int bN   = blockIdx.x * 128;
  const int lane = tid & 63;
  const int w    = tid >> 6;
  const int wm   = w >> 1, wn = w & 1;
  const int lrow = lane & 15, quad = lane >> 4;
  const int srow = lane >> 2, skc = (lane & 3) * 8;

  const u16* Ab = &A [(size_t)(bM + w*32 + srow)*K + skc];
  const u16* Bb = &Bt[(size_t)(bN + w*32 + srow)*K + skc];
  const size_t row16 = (size_t)16 * K;

  f32x4 acc[4][4];
  #pragma unroll
  for (int i = 0; i < 4; i++)
    #pragma unroll
    for (int j = 0; j < 4; j++)
      #pragma unroll
      for (int r = 0; r < 4; r++) acc[i][j][r] = 0.f;

  for (int k0 = 0; k0 < K; k0 += 32){
    gload16(Ab + k0,         &As[(w*32     )*32]);
    gload16(Ab + k0 + row16, &As[(w*32 + 16)*32]);
    gload16(Bb + k0,         &Bs[(w*32     )*32]);
    gload16(Bb + k0 + row16, &Bs[(w*32 + 16)*32]);
    __syncthreads();

    bf16x8 af[4], bfv[4];
    #pragma unroll
    for (int mf = 0; mf < 4; mf++)
      af[mf] = *(const bf16x8*)&As[(wm*64 + mf*16 + lrow)*32 + quad*8];
    #pragma unroll
    for (int nf = 0; nf < 4; nf++)
      bfv[nf] = *(const bf16x8*)&Bs[(wn*64 + nf*16 + lrow)*32 + quad*8];
    #pragma unroll
    for (int mf = 0; mf < 4; mf++)
      #pragma unroll
      for (int nf = 0; nf < 4; nf++)
        acc[mf][nf] = __builtin_amdgcn_mfma_f32_16x16x32_bf16(af[mf], bfv[nf], acc[mf][nf], 0, 0, 0);
    __syncthreads();
  }
  #pragma unroll
  for (int mf = 0; mf < 4; mf++){
    #pragma unroll
    for (int nf = 0; nf < 4; nf++){
      int gcol = bN + wn*64 + nf*16 + lrow;
      #pragma unroll
      for (int r = 0; r < 4; r++){
        int grow = bM + wm*64 + mf*16 + quad*4 + r;
        size_t idx = (size_t)grow*N + gcol;
        if constexpr (sizeof(TC) == 4) C[idx] = acc[mf][nf][r];
        else                           C[idx] = f2b(acc[mf][nf][r]);
      }
    }
  }
}

// ---------------- fallback mixed GEMM (harness-verified R0 path) ------------------------
template<typename TA, typename TC>
__global__ __launch_bounds__(256) void gemm_any(const TA* __restrict__ A,
    const float* __restrict__ Bw, TC* __restrict__ C, int M, int N, int K)
{
  __shared__ u16 As[128*40];
  __shared__ u16 Bs[128*40];
  const int tid  = threadIdx.x;
  const int bM   = blockIdx.y * 128;
  const int bN   = blockIdx.x * 128;
  const int lane = tid & 63;
  const int wid  = tid >> 6;
  const int wm   = wid >> 1, wn = wid & 1;
  const int lrow = lane & 15, quad = lane >> 4;

  f32x4 acc[4][4];
  #pragma unroll
  for (int i = 0; i < 4; i++)
    #pragma unroll
    for (int j = 0; j < 4; j++)
      #pragma unroll
      for (int r = 0; r < 4; r++) acc[i][j][r] = 0.f;

  for (int k0 = 0; k0 < K; k0 += 32){
    #pragma unroll
    for (int i = 0; i < 4; i++){
      int c = tid + i*256;
      int row = c >> 3, kc = (c & 7) * 4;
      u16 tmp[4];
      if constexpr (sizeof(TA) == 4){
        float4 v = *(const float4*)&A[(size_t)(bM + row)*K + k0 + kc];
        tmp[0] = f2b(v.x); tmp[1] = f2b(v.y); tmp[2] = f2b(v.z); tmp[3] = f2b(v.w);
      } else {
        *(uint2*)tmp = *(const uint2*)&A[(size_t)(bM + row)*K + k0 + kc];
      }
      *(uint2*)&As[row*40 + kc] = *(uint2*)tmp;
    }
    #pragma unroll
    for (int i = 0; i < 4; i++){
      int c = tid + i*256;
      int kr = c >> 5, nc = (c & 31) * 4;
      float4 v = *(const float4*)&Bw[(size_t)(k0 + kr)*N + bN + nc];
      Bs[(nc+0)*40 + kr] = f2b(v.x);
      Bs[(nc+1)*40 + kr] = f2b(v.y);
      Bs[(nc+2)*40 + kr] = f2b(v.z);
      Bs[(nc+3)*40 + kr] = f2b(v.w);
    }
    __syncthreads();
    bf16x8 af[4], bfv[4];
    #pragma unroll
    for (int mf = 0; mf < 4; mf++)
      af[mf] = *(const bf16x8*)&As[(wm*64 + mf*16 + lrow)*40 + quad*8];
    #pragma unroll
    for (int nf = 0; nf < 4; nf++)
      bfv[nf] = *(const bf16x8*)&Bs[(wn*64 + nf*16 + lrow)*40 + quad*8];
    #pragma unroll
    for (int mf = 0; mf < 4; mf++)
      #pragma unroll
      for (int nf = 0; nf < 4; nf++)
        acc[mf][nf] = __builtin_amdgcn_mfma_f32_16x16x32_bf16(af[mf], bfv[nf], acc[mf][nf], 0, 0, 0);
    __syncthreads();
  }
  #pragma unroll
  for (int mf = 0; mf < 4; mf++){
    #pragma unroll
    for (int nf = 0; nf < 4; nf++){
      int gcol = bN + wn*64 + nf*16 + lrow;
      #pragma unroll
      for (int r = 0; r < 4; r++){
        int grow = bM + wm*64 + mf*16 + quad*4 + r;
        size_t idx = (size_t)grow*N + gcol;
        if constexpr (sizeof(TC) == 4) C[idx] = acc[mf][nf][r];
        else                           C[idx] = f2b(acc[mf][nf][r]);
      }
    }
  }
}

// ---------------- partial interleaved RoPE on q (bf16 ws), in place ---------------------
__global__ void rope_q_kernel(u16* __restrict__ q){
  int gid = blockIdx.x * 256 + threadIdx.x;
  int t = gid >> 9;
  int r = gid & 511;
  int h = r >> 5;
  int i = r & 31;
  int pos = t & (S_LEN - 1);
  float freq = expf(-(float)i * (LN10000 / 32.f));
  float ang = (float)pos * freq;
  float sn, cs;
  sincosf(ang, &sn, &cs);
  size_t off = (size_t)t*HID + h*HD + 64 + 2*i;
  float a  = b2f(q[off]);
  float bb = b2f(q[off+1]);
  q[off]   = f2b(a*cs - bb*sn);
  q[off+1] = f2b(a*sn + bb*cs);
}

// ---------------- overlapped pooling + k RoPE; V written TRANSPOSED vT[b][d][w] ---------
__global__ void pool_rope_k(const u16* __restrict__ kv, const u16* __restrict__ gate,
                            const float* __restrict__ ape, u16* __restrict__ krot,
                            u16* __restrict__ vT, int str){
  const int d = threadIdx.x;   // 0..127
  const int w = blockIdx.x;    // 0..1023
  const int b = blockIdx.y;
  __shared__ float sh[HD];
  const bool hasprev = (w > 0);
  float gc[4], vc[4], gp[4], vp[4];
  float m = NEG_BIG;
  #pragma unroll
  for (int r = 0; r < 4; r++){
    size_t t = (size_t)(b*S_LEN + w*4 + r)*str;
    vc[r] = b2f(kv[t + 128 + d]);
    gc[r] = b2f(gate[t + 128 + d]) + ape[r*256 + 128 + d];
    m = fmaxf(m, gc[r]);
  }
  if (hasprev){
    #pragma unroll
    for (int r = 0; r < 4; r++){
      size_t t = (size_t)(b*S_LEN + (w-1)*4 + r)*str;
      vp[r] = b2f(kv[t + d]);
      gp[r] = b2f(gate[t + d]) + ape[r*256 + d];
      m = fmaxf(m, gp[r]);
    }
  }
  float s = 0.f, acc = 0.f;
  #pragma unroll
  for (int r = 0; r < 4; r++){
    float e = __expf(gc[r] - m); s += e; acc += e*vc[r];
  }
  if (hasprev){
    #pragma unroll
    for (int r = 0; r < 4; r++){
      float e = __expf(gp[r] - m); s += e; acc += e*vp[r];
    }
  }
  float pooled = acc / s;
  sh[d] = pooled;
  __syncthreads();
  float kr = pooled;
  if (d >= 64){
    int i = (d - 64) >> 1;
    float freq = expf(-(float)i * (LN10000 / 32.f));
    float ang = (float)(4*w) * freq;
    float sn, cs;
    sincosf(ang, &sn, &cs);
    if ((d & 1) == 0) kr = sh[d]*cs - sh[d+1]*sn;
    else              kr = sh[d-1]*sn + sh[d]*cs;
  }
  krot[(size_t)(b*NW + w)*HD + d] = f2b(kr);
  vT[(size_t)(b*HD + d)*NW + w]   = f2b(pooled);   // transposed for attn PV staging
}

// ---------------- MFMA flash attention, 32 q/wave, 128 q/block --------------------------
// 4 waves; wave owns 32 q-rows as two 16-row groups g=0,1. Swapped-operand MFMAs keep
// softmax stats per-lane (q = lane&15). Per chunk: stage K[64][128] + Vt[128][64] (both
// uint4->b128, Vt from pre-transposed vT), 2 barriers. K-frags and Vt-frags are read from
// LDS ONCE and used by both q-groups (2x arithmetic intensity vs R2); P round-trips a
// per-wave LDS strip (wave-synchronous). Block order reversed so heavy causal blocks
// launch first. LDS 54.3KB -> 2 blocks/CU; launch_bounds(256,2) leaves VGPR free (accO 64
// + qf 32 + accS 32 live). Fully-masked rows self-heal via sc==0 epilogue.
#define AQT 128
#define AKT 64
#define AKSTR 136  // u16: 272B rows (17*16B), frag reads 2-way free
#define AVSTR 72   // u16: 144B rows (9*16B)
#define APSTR 72
#define ATT_SCALE 0.088388347648318447f

__global__ __launch_bounds__(256, 2) void attn_kernel(
    const u16* __restrict__ qbuf, const u16* __restrict__ krot,
    const u16* __restrict__ vT, const float* __restrict__ sinks,
    u16* __restrict__ attnbuf)
{
  __shared__ u16 Ks[AKT*AKSTR];   // [k][d]   17408 B
  __shared__ u16 Vt[HD*AVSTR];    // [dv][k]  18432 B
  __shared__ u16 Pq[AQT*APSTR];   // [q][k]   18432 B

  const int tid  = threadIdx.x;
  const int q0   = (int)(gridDim.x - 1 - blockIdx.x) * AQT;  // heavy blocks first
  const int h    = blockIdx.y;
  const int b    = blockIdx.z;
  const int lane = tid & 63;
  const int wq   = tid >> 6;
  const int lrw  = lane & 15;
  const int quad = lane >> 4;
  const int qg0  = q0 + wq*32 + lrw;        // group-0 q-row of this lane
  // group-1 row = qg0 + 16

  // Q fragments in registers (B-operand layout: n=lrw, k=d0*32+quad*8+j)
  bf16x8 qf[2][4];
  #pragma unroll
  for (int g = 0; g < 2; g++){
    const u16* qrow = &qbuf[(size_t)(b*S_LEN + qg0 + g*16)*HID + h*HD];
    #pragma unroll
    for (int d0 = 0; d0 < 4; d0++)
      qf[g][d0] = *(const bf16x8*)&qrow[d0*32 + quad*8];
  }

  float m_run[2] = {NEG_BIG, NEG_BIG};
  float l_run[2] = {0.f, 0.f};
  f32x4 accO[2][8];
  #pragma unroll
  for (int g = 0; g < 2; g++)
    #pragma unroll
    for (int ds = 0; ds < 8; ds++)
      #pragma unroll
      for (int r = 0; r < 4; r++) accO[g][ds][r] = 0.f;

  const int kmax_tile = (q0 + AQT - 1 - 3) >> 2;
  int nchunk = (kmax_tile >> 6) + 1;
  if (nchunk > NW/AKT) nchunk = NW/AKT;

  for (int ch = 0; ch < nchunk; ch++){
    const int kc0 = ch * AKT;
    // stage K natural [k][d]: 1024 uint4 / 256 thr
    #pragma unroll
    for (int i = 0; i < 4; i++){
      int c = tid + i*256;
      int kl = c >> 4, cc = (c & 15) * 8;
      *(uint4*)&Ks[kl*AKSTR + cc] =
        *(const uint4*)&krot[(size_t)(b*NW + kc0 + kl)*HD + cc];
    }
    // stage Vt [dv][k] from pre-transposed vT: 1024 uint4 / 256 thr, b128 writes
    #pragma unroll
    for (int i = 0; i < 4; i++){
      int c = tid + i*256;
      int dv = c >> 3, cc = (c & 7) * 8;
      *(uint4*)&Vt[dv*AVSTR + cc] =
        *(const uint4*)&vT[(size_t)(b*HD + dv)*NW + kc0 + cc];
    }
    __syncthreads();

    // QK^T swapped, both groups share each K-frag read
    f32x4 accS[2][4];
    #pragma unroll
    for (int g = 0; g < 2; g++)
      #pragma unroll
      for (int ks = 0; ks < 4; ks++)
        #pragma unroll
        for (int r = 0; r < 4; r++) accS[g][ks][r] = 0.f;
    #pragma unroll
    for (int d0 = 0; d0 < 4; d0++){
      #pragma unroll
      for (int ks = 0; ks < 4; ks++){
        bf16x8 kf = *(const bf16x8*)&Ks[(ks*16 + lrw)*AKSTR + d0*32 + quad*8];
        accS[0][ks] = __builtin_amdgcn_mfma_f32_16x16x32_bf16(kf, qf[0][d0], accS[0][ks], 0, 0, 0);
        accS[1][ks] = __builtin_amdgcn_mfma_f32_16x16x32_bf16(kf, qf[1][d0], accS[1][ks], 0, 0, 0);
      }
    }

    // register softmax per group; P -> per-wave LDS strip (wave-synchronous)
    float alpha[2];
    #pragma unroll
    for (int g = 0; g < 2; g++){
      const int qg = qg0 + g*16;
      float p[16];
      float lmax = NEG_BIG;
      #pragma unroll
      for (int ks = 0; ks < 4; ks++)
        #pragma unroll
        for (int r = 0; r < 4; r++){
          int kg = kc0 + ks*16 + quad*4 + r;
          float s = (qg >= 4*kg + 3) ? accS[g][ks][r]*ATT_SCALE : NEG_BIG;
          p[ks*4 + r] = s;
          lmax = fmaxf(lmax, s);
        }
      lmax = fmaxf(lmax, __shfl_xor(lmax, 16));
      lmax = fmaxf(lmax, __shfl_xor(lmax, 32));
      float mnew = fmaxf(m_run[g], lmax);
      alpha[g] = __expf(m_run[g] - mnew);
      m_run[g] = mnew;
      float ls = 0.f;
      #pragma unroll
      for (int i = 0; i < 16; i++){
        float e = __expf(p[i] - mnew);
        p[i] = e; ls += e;
      }
      ls += __shfl_xor(ls, 16);
      ls += __shfl_xor(ls, 32);
      l_run[g] = l_run[g]*alpha[g] + ls;
      #pragma unroll
      for (int ks = 0; ks < 4; ks++){
        u16 pb[4];
        #pragma unroll
        for (int r = 0; r < 4; r++) pb[r] = f2b(p[ks*4 + r]);
        *(uint2*)&Pq[(wq*32 + g*16 + lrw)*APSTR + ks*16 + quad*4] = *(uint2*)pb;
      }
    }

    // rescale O^T (alpha lane-local: accO col = q = lrw)
    #pragma unroll
    for (int g = 0; g < 2; g++)
      #pragma unroll
      for (int ds = 0; ds < 8; ds++)
        #pragma unroll
        for (int r = 0; r < 4; r++) accO[g][ds][r] *= alpha[g];

    // PV swapped: O^T[dv][q] += Vt[dv][k] * P^T[k][q]; Vt-frags shared across groups
    #pragma unroll
    for (int kks = 0; kks < 2; kks++){
      bf16x8 pf0 = *(const bf16x8*)&Pq[(wq*32      + lrw)*APSTR + kks*32 + quad*8];
      bf16x8 pf1 = *(const bf16x8*)&Pq[(wq*32 + 16 + lrw)*APSTR + kks*32 + quad*8];
      #pragma unroll
      for (int ds = 0; ds < 8; ds++){
        bf16x8 av = *(const bf16x8*)&Vt[(ds*16 + lrw)*AVSTR + kks*32 + quad*8];
        accO[0][ds] = __builtin_amdgcn_mfma_f32_16x16x32_bf16(av, pf0, accO[0][ds], 0, 0, 0);
        accO[1][ds] = __builtin_amdgcn_mfma_f32_16x16x32_bf16(av, pf1, accO[1][ds], 0, 0, 0);
      }
    }
    __syncthreads();   // protect Ks/Vt for next chunk's staging
  }

  // sink epilogue per group (quads hold disjoint dv quarters of row q)
  const float snk = sinks[h];
  #pragma unroll
  for (int g = 0; g < 2; g++){
    float mf = fmaxf(m_run[g], snk);
    float em = __expf(m_run[g] - mf);
    float sc = em / (l_run[g]*em + __expf(snk - mf));
    size_t o = (size_t)(b*S_LEN + qg0 + g*16)*HID + h*HD;
    #pragma unroll
    for (int ds = 0; ds < 8; ds++){
      u16 ob[4];
      #pragma unroll
      for (int r = 0; r < 4; r++) ob[r] = f2b(accO[g][ds][r] * sc);
      *(uint2*)&attnbuf[o + ds*16 + quad*4] = *(uint2*)ob;
    }
  }
}

// ---------------------------------------------------------------------------------------
extern "C" void kernel_launch(void* const* d_in, const int* in_sizes, int n_in,
                              void* d_out, int out_size, void* d_ws, size_t ws_size,
                              hipStream_t stream)
{
  const float* hidden = (const float*)d_in[0];
  const float* wq     = (const float*)d_in[1];
  const float* wkv    = (const float*)d_in[2];
  const float* wgate  = (const float*)d_in[3];
  const float* ape    = (const float*)d_in[4];
  const float* sinks  = (const float*)d_in[5];
  const float* wo     = (const float*)d_in[6];

  const size_t NEED = ((size_t)TOK*HID*2 + (size_t)TOK*512 + (size_t)4*NW*HD
                     + (size_t)HID*HID + (size_t)512*HID) * sizeof(u16); // 87.0 MB

  if (ws_size >= NEED){
    u16* hid_bf = (u16*)d_ws;                         // TOK*HID       (also attnbuf)
    u16* qbuf   = hid_bf + (size_t)TOK*HID;           // TOK*HID
    u16* kvg    = qbuf   + (size_t)TOK*HID;           // TOK*512       (also woT)
    u16* krot   = kvg    + (size_t)TOK*512;           // 2*NW*HD
    u16* vTb    = krot   + (size_t)2*NW*HD;           // 2*HD*NW (transposed V)
    u16* wqT    = vTb    + (size_t)2*NW*HD;           // 2048*2048
    u16* wkvgT  = wqT    + (size_t)HID*HID;           // 512*2048
    u16* attnbuf = hid_bf;
    u16* woT     = kvg;

    cvt_bf16<<<(TOK*HID/8)/256, 256, 0, stream>>>(hidden, hid_bf);
    transpose_w<<<dim3(HID/32, HID/32), 256, 0, stream>>>(wq, wqT, HID, HID);
    transpose_w<<<dim3(256/32, HID/32), 256, 0, stream>>>(wkv,   wkvgT,            HID, 256);
    transpose_w<<<dim3(256/32, HID/32), 256, 0, stream>>>(wgate, wkvgT + (size_t)256*HID, HID, 256);
    gemm_bf16<u16><<<dim3(HID/128, TOK/128), 256, 0, stream>>>(hid_bf, wqT,   qbuf, TOK, HID, HID);
    gemm_bf16<u16><<<dim3(512/128, TOK/128), 256, 0, stream>>>(hid_bf, wkvgT, kvg,  TOK, 512, HID);
    rope_q_kernel<<<(TOK*NHEAD*32)/256, 256, 0, stream>>>(qbuf);
    pool_rope_k<<<dim3(NW, 2), 128, 0, stream>>>(kvg, kvg + 256, ape, krot, vTb, 512);
    attn_kernel<<<dim3(S_LEN/AQT, NHEAD, 2), 256, 0, stream>>>(qbuf, krot, vTb, sinks, attnbuf);
    transpose_w<<<dim3(HID/32, HID/32), 256, 0, stream>>>(wo, woT, HID, HID);   // kvg dead
    gemm_bf16<float><<<dim3(HID/128, TOK/128), 256, 0, stream>>>(attnbuf, woT, (float*)d_out, TOK, HID, HID);
  } else {
    // fallback: R0 verified GEMM path + new attn (pool writes vT layout in both paths)
    u16* qbuf    = (u16*)d_ws;
    u16* kvbuf   = qbuf    + (size_t)TOK*HID;
    u16* gatebuf = kvbuf   + (size_t)TOK*256;
    u16* krot    = gatebuf + (size_t)TOK*256;
    u16* vTb     = krot    + (size_t)2*NW*HD;
    u16* attnbuf = vTb     + (size_t)2*NW*HD;

    gemm_any<float,u16><<<dim3(HID/128, TOK/128), 256, 0, stream>>>(hidden, wq,    qbuf,    TOK, HID, HID);
    gemm_any<float,u16><<<dim3(256/128, TOK/128), 256, 0, stream>>>(hidden, wkv,   kvbuf,   TOK, 256, HID);
    gemm_any<float,u16><<<dim3(256/128, TOK/128), 256, 0, stream>>>(hidden, wgate, gatebuf, TOK, 256, HID);
    rope_q_kernel<<<(TOK*NHEAD*32)/256, 256, 0, stream>>>(qbuf);
    pool_rope_k<<<dim3(NW, 2), 128, 0, stream>>>(kvbuf, gatebuf, ape, krot, vTb, 256);
    attn_kernel<<<dim3(S_LEN/AQT, NHEAD, 2), 256, 0, stream>>>(qbuf, krot, vTb, sinks, attnbuf);
    gemm_any<u16,float><<<dim3(HID/128, TOK/128), 256, 0, stream>>>(attnbuf, wo, (float*)d_out, TOK, HID, HID);
  }
}

// Round 6
// 505.081 us; speedup vs baseline: 4.3308x; 1.0818x over previous
//
#include <hip/hip_runtime.h>
#include <math.h>

typedef unsigned short u16;
typedef unsigned int   u32;
typedef __bf16 bf16x8 __attribute__((ext_vector_type(8)));
typedef float  f32x4  __attribute__((ext_vector_type(4)));

#define S_LEN 4096
#define HID   2048
#define NHEAD 16
#define HD    128
#define NW    1024
#define TOK   8192
#define LN10000 9.2103403719761836f
#define NEG_BIG (-1e30f)

__device__ __forceinline__ float b2f(u16 u){
  union { u32 i; float f; } v; v.i = ((u32)u) << 16; return v.f;
}
__device__ __forceinline__ u16 f2b(float f){
  union { float f; u32 i; } v; v.f = f;
  return (u16)((v.i + 0x7FFFu + ((v.i >> 16) & 1u)) >> 16);
}

// ---------------- one-time f32 -> bf16 convert (hidden), 8 elems/thread -----------------
__global__ __launch_bounds__(256) void cvt_bf16(const float* __restrict__ in,
                                                u16* __restrict__ out){
  size_t i = (size_t)blockIdx.x*256 + threadIdx.x;
  float4 a = ((const float4*)in)[2*i];
  float4 b = ((const float4*)in)[2*i+1];
  u16 t[8];
  t[0]=f2b(a.x); t[1]=f2b(a.y); t[2]=f2b(a.z); t[3]=f2b(a.w);
  t[4]=f2b(b.x); t[5]=f2b(b.y); t[6]=f2b(b.z); t[7]=f2b(b.w);
  *(uint4*)&out[i*8] = *(uint4*)t;
}

// ---------------- one-time weight transpose+convert: f32[K][N] -> bf16[N][K] ------------
__global__ __launch_bounds__(256) void transpose_w(const float* __restrict__ in,
    u16* __restrict__ out, int K, int N){
  __shared__ float t[32][33];
  const int n0 = blockIdx.x*32, k0 = blockIdx.y*32;
  const int c = threadIdx.x & 31, r8 = threadIdx.x >> 5;
  #pragma unroll
  for (int i = 0; i < 4; i++)
    t[r8 + i*8][c] = in[(size_t)(k0 + r8 + i*8)*N + n0 + c];
  __syncthreads();
  #pragma unroll
  for (int i = 0; i < 4; i++)
    out[(size_t)(n0 + r8 + i*8)*K + k0 + c] = f2b(t[c][r8 + i*8]);
}

typedef __attribute__((address_space(3))) u16 as3_u16;
typedef __attribute__((address_space(1))) const u16 as1_u16;
__device__ __forceinline__ void gload16(const u16* g, u16* l){
  __builtin_amdgcn_global_load_lds((as1_u16*)g, (as3_u16*)l, 16, 0, 0);
}

// ---------------- 256x256 8-phase GEMM (T2+T3+T4+T5): C = A(M,K) @ Bt(N,K)^T ------------
// BK=64, 8 waves (2Mx4N), 512 thr, LDS 2x(A 32KB + B 32KB) dbuf = 128KB -> 1 block/CU.
// Half-tiles (128 rows x 64 k), issue order tile t+1: ph0={A-lo,B-lo}, ph1={B-hi},
// ph2={A-hi}. Consumption tile t: ph0 b(all)+a mf0-1, ph1 a mf2-3, ph2 a mf4-5 (A-hi),
// ph3 a mf6-7. Counted waits (per-wave, 2 loads/half-tile): vmcnt(6)@ph1 guards A-hi(t)
// (issued t-1 ph2); vmcnt(2)@ph3 guards t+1's A-lo/B-lo/B-hi, leaves A-hi(t+1) in
// flight. Raw s_barrier + sched_barrier(0) after every barrier (pins phase reads).
// T2 swizzle: 128B rows, u16col ^= (row&7)<<3 on BOTH sides (pre-swizzled per-lane
// global src for the linear-dest DMA + swizzled frag reads) -> conflict-free.
// launch_bounds(512,1): LDS caps occupancy at 1 block/CU anyway; uncapped VGPR = no spill.
template<typename TC>
__global__ __launch_bounds__(512, 1) void gemm256(const u16* __restrict__ A,
    const u16* __restrict__ Bt, TC* __restrict__ C, int M, int N, int K)
{
  __shared__ __align__(16) u16 LA[2][256*64];
  __shared__ __align__(16) u16 LB[2][256*64];
  const int tid  = threadIdx.x;
  const int lane = tid & 63;
  const int w    = tid >> 6;        // 0..7
  const int wm   = w & 1;
  const int wn   = w >> 1;          // 0..3
  const int lrw  = lane & 15;
  const int quad = lane >> 4;
  const int NB   = N >> 8;
  const int nwg  = gridDim.x;       // multiple of 8 for our shapes
  const int bid  = blockIdx.x;
  const int swz  = (bid & 7) * (nwg >> 3) + (bid >> 3);   // XCD-contiguous chunks
  const int bN   = (swz % NB) << 8;
  const int bM   = (swz / NB) << 8;

  // staging lane constants (dest linear, source pre-swizzled)
  const int rlo = lane >> 3;                   // row within 8-row group = (lds_row & 7)
  const int csw = ((lane & 7) ^ rlo) << 3;     // swizzled u16 col of this lane's 16B
  const int sr0 = w * 16;                      // wave's row base within a half-tile
  const int swr = (lrw & 7) << 3;              // read-side swizzle key
  const u16* Ag = A  + (size_t)bM * K + (size_t)rlo * K + csw;
  const u16* Bg = Bt + (size_t)bN * K + (size_t)rlo * K + csw;
  const size_t rK = (size_t)K;

  f32x4 acc[8][4];
  #pragma unroll
  for (int i = 0; i < 8; i++)
    #pragma unroll
    for (int j = 0; j < 4; j++)
      #pragma unroll
      for (int r = 0; r < 4; r++) acc[i][j][r] = 0.f;

  const int NT = K >> 6;

  // prologue: tile 0 into buf0, issue order A-lo, B-lo, B-hi, A-hi
  gload16(Ag + (size_t)(  0 + sr0    )*rK, &LA[0][(  0 + sr0    )*64]);
  gload16(Ag + (size_t)(  0 + sr0 + 8)*rK, &LA[0][(  0 + sr0 + 8)*64]);
  gload16(Bg + (size_t)(  0 + sr0    )*rK, &LB[0][(  0 + sr0    )*64]);
  gload16(Bg + (size_t)(  0 + sr0 + 8)*rK, &LB[0][(  0 + sr0 + 8)*64]);
  gload16(Bg + (size_t)(128 + sr0    )*rK, &LB[0][(128 + sr0    )*64]);
  gload16(Bg + (size_t)(128 + sr0 + 8)*rK, &LB[0][(128 + sr0 + 8)*64]);
  gload16(Ag + (size_t)(128 + sr0    )*rK, &LA[0][(128 + sr0    )*64]);
  gload16(Ag + (size_t)(128 + sr0 + 8)*rK, &LA[0][(128 + sr0 + 8)*64]);
  asm volatile("s_waitcnt vmcnt(2)" ::: "memory");   // A-lo,B-lo,B-hi landed; A-hi in flight
  __builtin_amdgcn_s_barrier();
  __builtin_amdgcn_sched_barrier(0);

  for (int t = 0; t < NT; ++t){
    const int cur = t & 1, nxt = cur ^ 1;
    const int kn  = ((t + 1) & (NT - 1)) << 6;       // wrapped prefetch k (uniform counts)
    const u16* la = &LA[cur][0];
    const u16* lb = &LB[cur][0];
    u16* sa = &LA[nxt][0];
    u16* sb = &LB[nxt][0];

    bf16x8 bfr[4][2], afr[2][2];

    // ---- phase 0: issue A-lo,B-lo(t+1); read b all + a mf0,1; MFMA quarter 0
    gload16(Ag + (size_t)(  0 + sr0    )*rK + kn, &sa[(  0 + sr0    )*64]);
    gload16(Ag + (size_t)(  0 + sr0 + 8)*rK + kn, &sa[(  0 + sr0 + 8)*64]);
    gload16(Bg + (size_t)(  0 + sr0    )*rK + kn, &sb[(  0 + sr0    )*64]);
    gload16(Bg + (size_t)(  0 + sr0 + 8)*rK + kn, &sb[(  0 + sr0 + 8)*64]);
    #pragma unroll
    for (int nf = 0; nf < 4; nf++)
      #pragma unroll
      for (int kh = 0; kh < 2; kh++)
        bfr[nf][kh] = *(const bf16x8*)&lb[(wn*16 + nf*64 + lrw)*64 + ((kh*32 + quad*8) ^ swr)];
    #pragma unroll
    for (int i = 0; i < 2; i++)
      #pragma unroll
      for (int kh = 0; kh < 2; kh++)
        afr[i][kh] = *(const bf16x8*)&la[(wm*16 + (0+i)*32 + lrw)*64 + ((kh*32 + quad*8) ^ swr)];
    __builtin_amdgcn_s_barrier();
    __builtin_amdgcn_sched_barrier(0);
    __builtin_amdgcn_s_setprio(1);
    #pragma unroll
    for (int i = 0; i < 2; i++)
      #pragma unroll
      for (int nf = 0; nf < 4; nf++)
        #pragma unroll
        for (int kh = 0; kh < 2; kh++)
          acc[0+i][nf] = __builtin_amdgcn_mfma_f32_16x16x32_bf16(afr[i][kh], bfr[nf][kh], acc[0+i][nf], 0, 0, 0);
    __builtin_amdgcn_s_setprio(0);
    __builtin_amdgcn_s_barrier();
    __builtin_amdgcn_sched_barrier(0);

    // ---- phase 1: issue B-hi(t+1); read a mf2,3; vmcnt(6) guards A-hi(t)
    gload16(Bg + (size_t)(128 + sr0    )*rK + kn, &sb[(128 + sr0    )*64]);
    gload16(Bg + (size_t)(128 + sr0 + 8)*rK + kn, &sb[(128 + sr0 + 8)*64]);
    #pragma unroll
    for (int i = 0; i < 2; i++)
      #pragma unroll
      for (int kh = 0; kh < 2; kh++)
        afr[i][kh] = *(const bf16x8*)&la[(wm*16 + (2+i)*32 + lrw)*64 + ((kh*32 + quad*8) ^ swr)];
    asm volatile("s_waitcnt vmcnt(6)" ::: "memory");
    __builtin_amdgcn_s_barrier();
    __builtin_amdgcn_sched_barrier(0);
    __builtin_amdgcn_s_setprio(1);
    #pragma unroll
    for (int i = 0; i < 2; i++)
      #pragma unroll
      for (int nf = 0; nf < 4; nf++)
        #pragma unroll
        for (int kh = 0; kh < 2; kh++)
          acc[2+i][nf] = __builtin_amdgcn_mfma_f32_16x16x32_bf16(afr[i][kh], bfr[nf][kh], acc[2+i][nf], 0, 0, 0);
    __builtin_amdgcn_s_setprio(0);
    __builtin_amdgcn_s_barrier();
    __builtin_amdgcn_sched_barrier(0);

    // ---- phase 2: issue A-hi(t+1); read a mf4,5 (A-hi of t, guarded by ph1)
    gload16(Ag + (size_t)(128 + sr0    )*rK + kn, &sa[(128 + sr0    )*64]);
    gload16(Ag + (size_t)(128 + sr0 + 8)*rK + kn, &sa[(128 + sr0 + 8)*64]);
    #pragma unroll
    for (int i = 0; i < 2; i++)
      #pragma unroll
      for (int kh = 0; kh < 2; kh++)
        afr[i][kh] = *(const bf16x8*)&la[(wm*16 + (4+i)*32 + lrw)*64 + ((kh*32 + quad*8) ^ swr)];
    __builtin_amdgcn_s_barrier();
    __builtin_amdgcn_sched_barrier(0);
    __builtin_amdgcn_s_setprio(1);
    #pragma unroll
    for (int i = 0; i < 2; i++)
      #pragma unroll
      for (int nf = 0; nf < 4; nf++)
        #pragma unroll
        for (int kh = 0; kh < 2; kh++)
          acc[4+i][nf] = __builtin_amdgcn_mfma_f32_16x16x32_bf16(afr[i][kh], bfr[nf][kh], acc[4+i][nf], 0, 0, 0);
    __builtin_amdgcn_s_setprio(0);
    __builtin_amdgcn_s_barrier();
    __builtin_amdgcn_sched_barrier(0);

    // ---- phase 3: read a mf6,7; vmcnt(2) guards next tile's A-lo/B-lo/B-hi
    #pragma unroll
    for (int i = 0; i < 2; i++)
      #pragma unroll
      for (int kh = 0; kh < 2; kh++)
        afr[i][kh] = *(const bf16x8*)&la[(wm*16 + (6+i)*32 + lrw)*64 + ((kh*32 + quad*8) ^ swr)];
    asm volatile("s_waitcnt vmcnt(2)" ::: "memory");
    __builtin_amdgcn_s_barrier();
    __builtin_amdgcn_sched_barrier(0);
    __builtin_amdgcn_s_setprio(1);
    #pragma unroll
    for (int i = 0; i < 2; i++)
      #pragma unroll
      for (int nf = 0; nf < 4; nf++)
        #pragma unroll
        for (int kh = 0; kh < 2; kh++)
          acc[6+i][nf] = __builtin_amdgcn_mfma_f32_16x16x32_bf16(afr[i][kh], bfr[nf][kh], acc[6+i][nf], 0, 0, 0);
    __builtin_amdgcn_s_setprio(0);
    __builtin_amdgcn_s_barrier();
    __builtin_amdgcn_sched_barrier(0);
  }

  asm volatile("s_waitcnt vmcnt(0)" ::: "memory");   // drain wrap-prefetch before exit

  #pragma unroll
  for (int mf = 0; mf < 8; mf++){
    const int orow0 = bM + wm*16 + mf*32 + quad*4;
    #pragma unroll
    for (int nf = 0; nf < 4; nf++){
      const int ocol = bN + wn*16 + nf*64 + lrw;
      #pragma unroll
      for (int r = 0; r < 4; r++){
        size_t idx = (size_t)(orow0 + r)*N + ocol;
        if constexpr (sizeof(TC) == 4) C[idx] = acc[mf][nf][r];
        else                           C[idx] = f2b(acc[mf][nf][r]);
      }
    }
  }
}

// ---------------- m97-structure bf16 GEMM (kept for N=512 kvg) --------------------------
template<typename TC>
__global__ __launch_bounds__(256) void gemm_bf16(const u16* __restrict__ A,
    const u16* __restrict__ Bt, TC* __restrict__ C, int M, int N, int K)
{
  __shared__ u16 As[128*32];
  __shared__ u16 Bs[128*32];
  const int tid  = threadIdx.x;
  const int bM   = blockIdx.y * 128;
  const int bN   = blockIdx.x * 128;
  const int lane = tid & 63;
  const int w    = tid >> 6;
  const int wm   = w >> 1, wn = w & 1;
  const int lrow = lane & 15, quad = lane >> 4;
  const int srow = lane >> 2, skc = (lane & 3) * 8;

  const u16* Ab = &A [(size_t)(bM + w*32 + srow)*K + skc];
  const u16* Bb = &Bt[(size_t)(bN + w*32 + srow)*K + skc];
  const size_t row16 = (size_t)16 * K;

  f32x4 acc[4][4];
  #pragma unroll
  for (int i = 0; i < 4; i++)
    #pragma unroll
    for (int j = 0; j < 4; j++)
      #pragma unroll
      for (int r = 0; r < 4; r++) acc[i][j][r] = 0.f;

  for (int k0 = 0; k0 < K; k0 += 32){
    gload16(Ab + k0,         &As[(w*32     )*32]);
    gload16(Ab + k0 + row16, &As[(w*32 + 16)*32]);
    gload16(Bb + k0,         &Bs[(w*32     )*32]);
    gload16(Bb + k0 + row16, &Bs[(w*32 + 16)*32]);
    __syncthreads();

    bf16x8 af[4], bfv[4];
    #pragma unroll
    for (int mf = 0; mf < 4; mf++)
      af[mf] = *(const bf16x8*)&As[(wm*64 + mf*16 + lrow)*32 + quad*8];
    #pragma unroll
    for (int nf = 0; nf < 4; nf++)
      bfv[nf] = *(const bf16x8*)&Bs[(wn*64 + nf*16 + lrow)*32 + quad*8];
    #pragma unroll
    for (int mf = 0; mf < 4; mf++)
      #pragma unroll
      for (int nf = 0; nf < 4; nf++)
        acc[mf][nf] = __builtin_amdgcn_mfma_f32_16x16x32_bf16(af[mf], bfv[nf], acc[mf][nf], 0, 0, 0);
    __syncthreads();
  }
  #pragma unroll
  for (int mf = 0; mf < 4; mf++){
    #pragma unroll
    for (int nf = 0; nf < 4; nf++){
      int gcol = bN + wn*64 + nf*16 + lrow;
      #pragma unroll
      for (int r = 0; r < 4; r++){
        int grow = bM + wm*64 + mf*16 + quad*4 + r;
        size_t idx = (size_t)grow*N + gcol;
        if constexpr (sizeof(TC) == 4) C[idx] = acc[mf][nf][r];
        else                           C[idx] = f2b(acc[mf][nf][r]);
      }
    }
  }
}

// ---------------- fallback mixed GEMM (harness-verified R0 path) ------------------------
template<typename TA, typename TC>
__global__ __launch_bounds__(256) void gemm_any(const TA* __restrict__ A,
    const float* __restrict__ Bw, TC* __restrict__ C, int M, int N, int K)
{
  __shared__ u16 As[128*40];
  __shared__ u16 Bs[128*40];
  const int tid  = threadIdx.x;
  const int bM   = blockIdx.y * 128;
  const int bN   = blockIdx.x * 128;
  const int lane = tid & 63;
  const int wid  = tid >> 6;
  const int wm   = wid >> 1, wn = wid & 1;
  const int lrow = lane & 15, quad = lane >> 4;

  f32x4 acc[4][4];
  #pragma unroll
  for (int i = 0; i < 4; i++)
    #pragma unroll
    for (int j = 0; j < 4; j++)
      #pragma unroll
      for (int r = 0; r < 4; r++) acc[i][j][r] = 0.f;

  for (int k0 = 0; k0 < K; k0 += 32){
    #pragma unroll
    for (int i = 0; i < 4; i++){
      int c = tid + i*256;
      int row = c >> 3, kc = (c & 7) * 4;
      u16 tmp[4];
      if constexpr (sizeof(TA) == 4){
        float4 v = *(const float4*)&A[(size_t)(bM + row)*K + k0 + kc];
        tmp[0] = f2b(v.x); tmp[1] = f2b(v.y); tmp[2] = f2b(v.z); tmp[3] = f2b(v.w);
      } else {
        *(uint2*)tmp = *(const uint2*)&A[(size_t)(bM + row)*K + k0 + kc];
      }
      *(uint2*)&As[row*40 + kc] = *(uint2*)tmp;
    }
    #pragma unroll
    for (int i = 0; i < 4; i++){
      int c = tid + i*256;
      int kr = c >> 5, nc = (c & 31) * 4;
      float4 v = *(const float4*)&Bw[(size_t)(k0 + kr)*N + bN + nc];
      Bs[(nc+0)*40 + kr] = f2b(v.x);
      Bs[(nc+1)*40 + kr] = f2b(v.y);
      Bs[(nc+2)*40 + kr] = f2b(v.z);
      Bs[(nc+3)*40 + kr] = f2b(v.w);
    }
    __syncthreads();
    bf16x8 af[4], bfv[4];
    #pragma unroll
    for (int mf = 0; mf < 4; mf++)
      af[mf] = *(const bf16x8*)&As[(wm*64 + mf*16 + lrow)*40 + quad*8];
    #pragma unroll
    for (int nf = 0; nf < 4; nf++)
      bfv[nf] = *(const bf16x8*)&Bs[(wn*64 + nf*16 + lrow)*40 + quad*8];
    #pragma unroll
    for (int mf = 0; mf < 4; mf++)
      #pragma unroll
      for (int nf = 0; nf < 4; nf++)
        acc[mf][nf] = __builtin_amdgcn_mfma_f32_16x16x32_bf16(af[mf], bfv[nf], acc[mf][nf], 0, 0, 0);
    __syncthreads();
  }
  #pragma unroll
  for (int mf = 0; mf < 4; mf++){
    #pragma unroll
    for (int nf = 0; nf < 4; nf++){
      int gcol = bN + wn*64 + nf*16 + lrow;
      #pragma unroll
      for (int r = 0; r < 4; r++){
        int grow = bM + wm*64 + mf*16 + quad*4 + r;
        size_t idx = (size_t)grow*N + gcol;
        if constexpr (sizeof(TC) == 4) C[idx] = acc[mf][nf][r];
        else                           C[idx] = f2b(acc[mf][nf][r]);
      }
    }
  }
}

// ---------------- partial interleaved RoPE on q (bf16 ws), in place ---------------------
__global__ void rope_q_kernel(u16* __restrict__ q){
  int gid = blockIdx.x * 256 + threadIdx.x;
  int t = gid >> 9;
  int r = gid & 511;
  int h = r >> 5;
  int i = r & 31;
  int pos = t & (S_LEN - 1);
  float freq = expf(-(float)i * (LN10000 / 32.f));
  float ang = (float)pos * freq;
  float sn, cs;
  sincosf(ang, &sn, &cs);
  size_t off = (size_t)t*HID + h*HD + 64 + 2*i;
  float a  = b2f(q[off]);
  float bb = b2f(q[off+1]);
  q[off]   = f2b(a*cs - bb*sn);
  q[off+1] = f2b(a*sn + bb*cs);
}

// ---------------- overlapped pooling + k RoPE; V written TRANSPOSED vT[b][d][w] ---------
__global__ void pool_rope_k(const u16* __restrict__ kv, const u16* __restrict__ gate,
                            const float* __restrict__ ape, u16* __restrict__ krot,
                            u16* __restrict__ vT, int str){
  const int d = threadIdx.x;   // 0..127
  const int w = blockIdx.x;    // 0..1023
  const int b = blockIdx.y;
  __shared__ float sh[HD];
  const bool hasprev = (w > 0);
  float gc[4], vc[4], gp[4], vp[4];
  float m = NEG_BIG;
  #pragma unroll
  for (int r = 0; r < 4; r++){
    size_t t = (size_t)(b*S_LEN + w*4 + r)*str;
    vc[r] = b2f(kv[t + 128 + d]);
    gc[r] = b2f(gate[t + 128 + d]) + ape[r*256 + 128 + d];
    m = fmaxf(m, gc[r]);
  }
  if (hasprev){
    #pragma unroll
    for (int r = 0; r < 4; r++){
      size_t t = (size_t)(b*S_LEN + (w-1)*4 + r)*str;
      vp[r] = b2f(kv[t + d]);
      gp[r] = b2f(gate[t + d]) + ape[r*256 + d];
      m = fmaxf(m, gp[r]);
    }
  }
  float s = 0.f, acc = 0.f;
  #pragma unroll
  for (int r = 0; r < 4; r++){
    float e = __expf(gc[r] - m); s += e; acc += e*vc[r];
  }
  if (hasprev){
    #pragma unroll
    for (int r = 0; r < 4; r++){
      float e = __expf(gp[r] - m); s += e; acc += e*vp[r];
    }
  }
  float pooled = acc / s;
  sh[d] = pooled;
  __syncthreads();
  float kr = pooled;
  if (d >= 64){
    int i = (d - 64) >> 1;
    float freq = expf(-(float)i * (LN10000 / 32.f));
    float ang = (float)(4*w) * freq;
    float sn, cs;
    sincosf(ang, &sn, &cs);
    if ((d & 1) == 0) kr = sh[d]*cs - sh[d+1]*sn;
    else              kr = sh[d-1]*sn + sh[d]*cs;
  }
  krot[(size_t)(b*NW + w)*HD + d] = f2b(kr);
  vT[(size_t)(b*HD + d)*NW + w]   = f2b(pooled);   // transposed for attn PV staging
}

// ---------------- MFMA flash attention (unchanged from passing R3) ----------------------
#define AQT 128
#define AKT 64
#define AKSTR 136
#define AVSTR 72
#define APSTR 72
#define ATT_SCALE 0.088388347648318447f

__global__ __launch_bounds__(256, 2) void attn_kernel(
    const u16* __restrict__ qbuf, const u16* __restrict__ krot,
    const u16* __restrict__ vT, const float* __restrict__ sinks,
    u16* __restrict__ attnbuf)
{
  __shared__ u16 Ks[AKT*AKSTR];
  __shared__ u16 Vt[HD*AVSTR];
  __shared__ u16 Pq[AQT*APSTR];

  const int tid  = threadIdx.x;
  const int q0   = (int)(gridDim.x - 1 - blockIdx.x) * AQT;
  const int h    = blockIdx.y;
  const int b    = blockIdx.z;
  const int lane = tid & 63;
  const int wq   = tid >> 6;
  const int lrw  = lane & 15;
  const int quad = lane >> 4;
  const int qg0  = q0 + wq*32 + lrw;

  bf16x8 qf[2][4];
  #pragma unroll
  for (int g = 0; g < 2; g++){
    const u16* qrow = &qbuf[(size_t)(b*S_LEN + qg0 + g*16)*HID + h*HD];
    #pragma unroll
    for (int d0 = 0; d0 < 4; d0++)
      qf[g][d0] = *(const bf16x8*)&qrow[d0*32 + quad*8];
  }

  float m_run[2] = {NEG_BIG, NEG_BIG};
  float l_run[2] = {0.f, 0.f};
  f32x4 accO[2][8];
  #pragma unroll
  for (int g = 0; g < 2; g++)
    #pragma unroll
    for (int ds = 0; ds < 8; ds++)
      #pragma unroll
      for (int r = 0; r < 4; r++) accO[g][ds][r] = 0.f;

  const int kmax_tile = (q0 + AQT - 1 - 3) >> 2;
  int nchunk = (kmax_tile >> 6) + 1;
  if (nchunk > NW/AKT) nchunk = NW/AKT;

  for (int ch = 0; ch < nchunk; ch++){
    const int kc0 = ch * AKT;
    #pragma unroll
    for (int i = 0; i < 4; i++){
      int c = tid + i*256;
      int kl = c >> 4, cc = (c & 15) * 8;
      *(uint4*)&Ks[kl*AKSTR + cc] =
        *(const uint4*)&krot[(size_t)(b*NW + kc0 + kl)*HD + cc];
    }
    #pragma unroll
    for (int i = 0; i < 4; i++){
      int c = tid + i*256;
      int dv = c >> 3, cc = (c & 7) * 8;
      *(uint4*)&Vt[dv*AVSTR + cc] =
        *(const uint4*)&vT[(size_t)(b*HD + dv)*NW + kc0 + cc];
    }
    __syncthreads();

    f32x4 accS[2][4];
    #pragma unroll
    for (int g = 0; g < 2; g++)
      #pragma unroll
      for (int ks = 0; ks < 4; ks++)
        #pragma unroll
        for (int r = 0; r < 4; r++) accS[g][ks][r] = 0.f;
    #pragma unroll
    for (int d0 = 0; d0 < 4; d0++){
      #pragma unroll
      for (int ks = 0; ks < 4; ks++){
        bf16x8 kf = *(const bf16x8*)&Ks[(ks*16 + lrw)*AKSTR + d0*32 + quad*8];
        accS[0][ks] = __builtin_amdgcn_mfma_f32_16x16x32_bf16(kf, qf[0][d0], accS[0][ks], 0, 0, 0);
        accS[1][ks] = __builtin_amdgcn_mfma_f32_16x16x32_bf16(kf, qf[1][d0], accS[1][ks], 0, 0, 0);
      }
    }

    float alpha[2];
    #pragma unroll
    for (int g = 0; g < 2; g++){
      const int qg = qg0 + g*16;
      float p[16];
      float lmax = NEG_BIG;
      #pragma unroll
      for (int ks = 0; ks < 4; ks++)
        #pragma unroll
        for (int r = 0; r < 4; r++){
          int kg = kc0 + ks*16 + quad*4 + r;
          float s = (qg >= 4*kg + 3) ? accS[g][ks][r]*ATT_SCALE : NEG_BIG;
          p[ks*4 + r] = s;
          lmax = fmaxf(lmax, s);
        }
      lmax = fmaxf(lmax, __shfl_xor(lmax, 16));
      lmax = fmaxf(lmax, __shfl_xor(lmax, 32));
      float mnew = fmaxf(m_run[g], lmax);
      alpha[g] = __expf(m_run[g] - mnew);
      m_run[g] = mnew;
      float ls = 0.f;
      #pragma unroll
      for (int i = 0; i < 16; i++){
        float e = __expf(p[i] - mnew);
        p[i] = e; ls += e;
      }
      ls += __shfl_xor(ls, 16);
      ls += __shfl_xor(ls, 32);
      l_run[g] = l_run[g]*alpha[g] + ls;
      #pragma unroll
      for (int ks = 0; ks < 4; ks++){
        u16 pb[4];
        #pragma unroll
        for (int r = 0; r < 4; r++) pb[r] = f2b(p[ks*4 + r]);
        *(uint2*)&Pq[(wq*32 + g*16 + lrw)*APSTR + ks*16 + quad*4] = *(uint2*)pb;
      }
    }

    #pragma unroll
    for (int g = 0; g < 2; g++)
      #pragma unroll
      for (int ds = 0; ds < 8; ds++)
        #pragma unroll
        for (int r = 0; r < 4; r++) accO[g][ds][r] *= alpha[g];

    #pragma unroll
    for (int kks = 0; kks < 2; kks++){
      bf16x8 pf0 = *(const bf16x8*)&Pq[(wq*32      + lrw)*APSTR + kks*32 + quad*8];
      bf16x8 pf1 = *(const bf16x8*)&Pq[(wq*32 + 16 + lrw)*APSTR + kks*32 + quad*8];
      #pragma unroll
      for (int ds = 0; ds < 8; ds++){
        bf16x8 av = *(const bf16x8*)&Vt[(ds*16 + lrw)*AVSTR + kks*32 + quad*8];
        accO[0][ds] = __builtin_amdgcn_mfma_f32_16x16x32_bf16(av, pf0, accO[0][ds], 0, 0, 0);
        accO[1][ds] = __builtin_amdgcn_mfma_f32_16x16x32_bf16(av, pf1, accO[1][ds], 0, 0, 0);
      }
    }
    __syncthreads();
  }

  const float snk = sinks[h];
  #pragma unroll
  for (int g = 0; g < 2; g++){
    float mf = fmaxf(m_run[g], snk);
    float em = __expf(m_run[g] - mf);
    float sc = em / (l_run[g]*em + __expf(snk - mf));
    size_t o = (size_t)(b*S_LEN + qg0 + g*16)*HID + h*HD;
    #pragma unroll
    for (int ds = 0; ds < 8; ds++){
      u16 ob[4];
      #pragma unroll
      for (int r = 0; r < 4; r++) ob[r] = f2b(accO[g][ds][r] * sc);
      *(uint2*)&attnbuf[o + ds*16 + quad*4] = *(uint2*)ob;
    }
  }
}

// ---------------------------------------------------------------------------------------
extern "C" void kernel_launch(void* const* d_in, const int* in_sizes, int n_in,
                              void* d_out, int out_size, void* d_ws, size_t ws_size,
                              hipStream_t stream)
{
  const float* hidden = (const float*)d_in[0];
  const float* wq     = (const float*)d_in[1];
  const float* wkv    = (const float*)d_in[2];
  const float* wgate  = (const float*)d_in[3];
  const float* ape    = (const float*)d_in[4];
  const float* sinks  = (const float*)d_in[5];
  const float* wo     = (const float*)d_in[6];

  const size_t NEED = ((size_t)TOK*HID*2 + (size_t)TOK*512 + (size_t)4*NW*HD
                     + (size_t)HID*HID + (size_t)512*HID) * sizeof(u16); // 87.0 MB

  if (ws_size >= NEED){
    u16* hid_bf = (u16*)d_ws;                         // TOK*HID       (also attnbuf)
    u16* qbuf   = hid_bf + (size_t)TOK*HID;           // TOK*HID
    u16* kvg    = qbuf   + (size_t)TOK*HID;           // TOK*512       (also woT)
    u16* krot   = kvg    + (size_t)TOK*512;           // 2*NW*HD
    u16* vTb    = krot   + (size_t)2*NW*HD;           // 2*HD*NW (transposed V)
    u16* wqT    = vTb    + (size_t)2*NW*HD;           // 2048*2048
    u16* wkvgT  = wqT    + (size_t)HID*HID;           // 512*2048
    u16* attnbuf = hid_bf;
    u16* woT     = kvg;

    cvt_bf16<<<(TOK*HID/8)/256, 256, 0, stream>>>(hidden, hid_bf);
    transpose_w<<<dim3(HID/32, HID/32), 256, 0, stream>>>(wq, wqT, HID, HID);
    transpose_w<<<dim3(256/32, HID/32), 256, 0, stream>>>(wkv,   wkvgT,            HID, 256);
    transpose_w<<<dim3(256/32, HID/32), 256, 0, stream>>>(wgate, wkvgT + (size_t)256*HID, HID, 256);
    gemm256<u16><<<dim3((TOK/256)*(HID/256)), 512, 0, stream>>>(hid_bf, wqT, qbuf, TOK, HID, HID);
    gemm_bf16<u16><<<dim3(512/128, TOK/128), 256, 0, stream>>>(hid_bf, wkvgT, kvg,  TOK, 512, HID);
    rope_q_kernel<<<(TOK*NHEAD*32)/256, 256, 0, stream>>>(qbuf);
    pool_rope_k<<<dim3(NW, 2), 128, 0, stream>>>(kvg, kvg + 256, ape, krot, vTb, 512);
    attn_kernel<<<dim3(S_LEN/AQT, NHEAD, 2), 256, 0, stream>>>(qbuf, krot, vTb, sinks, attnbuf);
    transpose_w<<<dim3(HID/32, HID/32), 256, 0, stream>>>(wo, woT, HID, HID);   // kvg dead
    gemm256<float><<<dim3((TOK/256)*(HID/256)), 512, 0, stream>>>(attnbuf, woT, (float*)d_out, TOK, HID, HID);
  } else {
    // fallback: R0 verified GEMM path + attn (pool writes vT layout in both paths)
    u16* qbuf    = (u16*)d_ws;
    u16* kvbuf   = qbuf    + (size_t)TOK*HID;
    u16* gatebuf = kvbuf   + (size_t)TOK*256;
    u16* krot    = gatebuf + (size_t)TOK*256;
    u16* vTb     = krot    + (size_t)2*NW*HD;
    u16* attnbuf = vTb     + (size_t)2*NW*HD;

    gemm_any<float,u16><<<dim3(HID/128, TOK/128), 256, 0, stream>>>(hidden, wq,    qbuf,    TOK, HID, HID);
    gemm_any<float,u16><<<dim3(256/128, TOK/128), 256, 0, stream>>>(hidden, wkv,   kvbuf,   TOK, 256, HID);
    gemm_any<float,u16><<<dim3(256/128, TOK/128), 256, 0, stream>>>(hidden, wgate, gatebuf, TOK, 256, HID);
    rope_q_kernel<<<(TOK*NHEAD*32)/256, 256, 0, stream>>>(qbuf);
    pool_rope_k<<<dim3(NW, 2), 128, 0, stream>>>(kvbuf, gatebuf, ape, krot, vTb, 256);
    attn_kernel<<<dim3(S_LEN/AQT, NHEAD, 2), 256, 0, stream>>>(qbuf, krot, vTb, sinks, attnbuf);
    gemm_any<u16,float><<<dim3(HID/128, TOK/128), 256, 0, stream>>>(attnbuf, wo, (float*)d_out, TOK, HID, HID);
  }
}